// Round 14
// baseline (164.880 us; speedup 1.0000x reference)
//
#include <hip/hip_runtime.h>
#include <math.h>

typedef short short8 __attribute__((ext_vector_type(8)));
typedef float f32x4 __attribute__((ext_vector_type(4)));
typedef float f32x16 __attribute__((ext_vector_type(16)));

#define GLB_CP(p) ((const __attribute__((address_space(1))) void*)(p))
#define LDS_CP(p) ((__attribute__((address_space(3))) void*)(p))

__device__ __forceinline__ float2 cmul(float2 a, float2 b) {
    return make_float2(a.x * b.x - a.y * b.y, a.x * b.y + a.y * b.x);
}

__device__ __forceinline__ ushort f2bf(float f) {
    uint u = __float_as_uint(f);
    uint r = (u + 0x7FFFu + ((u >> 16) & 1u)) >> 16;
    return (ushort)r;
}

// ---- prep: conv2 weights -> wt2[tap][icg][oc][ic8] bf16 ; fc1 weights -> bf16 ----
__global__ __launch_bounds__(256) void prep_kernel(
    const float* __restrict__ c2w, const float* __restrict__ f1w,
    ushort* __restrict__ wt2, ushort* __restrict__ wf1)
{
    int i = blockIdx.x * 256 + threadIdx.x;
    if (i < 18432) {
        int icl = i & 7;
        int t = i >> 3;
        int oc = t & 63;
        int t2 = t >> 6;
        int icg = t2 & 3;
        int tap = t2 >> 2;
        int ic = icg * 8 + icl;
        wt2[i] = f2bf(c2w[(oc * 32 + ic) * 9 + tap]);
    } else if (i < 18432 + 1179648) {
        int j = i - 18432;
        wf1[j] = f2bf(f1w[j]);
    }
}

// ---- conv1 + relu -> h1b[b][icg][pix][ic8] bf16 (fully parallel, r3-proven) ----
__global__ __launch_bounds__(256) void conv1_kernel(
    const float* __restrict__ x, const float* __restrict__ w1,
    const float* __restrict__ b1, ushort* __restrict__ h1b)
{
    __shared__ float wl[288];
    __shared__ float bl[32];
    int tid = threadIdx.x;
    for (int e = tid; e < 288; e += 256) wl[e] = w1[e];
    if (tid < 32) bl[tid] = b1[tid];
    __syncthreads();
    int e = blockIdx.x * 256 + tid;          // 2048*676*4 total, exact grid
    int icg = e & 3;
    int t = e >> 2;
    int pix = t % 676;
    int b = t / 676;
    int y = pix / 26, xc = pix % 26;
    const float* xp = x + b * 784 + y * 28 + xc;
    float in9[9];
#pragma unroll
    for (int ky = 0; ky < 3; ++ky)
#pragma unroll
        for (int kx = 0; kx < 3; ++kx) in9[ky * 3 + kx] = xp[ky * 28 + kx];
    short8 outv;
#pragma unroll
    for (int o = 0; o < 8; ++o) {
        int oc = icg * 8 + o;
        float acc = bl[oc];
#pragma unroll
        for (int k = 0; k < 9; ++k) acc = fmaf(in9[k], wl[oc * 9 + k], acc);
        outv[o] = (short)f2bf(fmaxf(acc, 0.f));
    }
    *(short8*)&h1b[((b * 4 + icg) * 676 + pix) * 8] = outv;
}

// ---- conv2 persistent: 512 blocks x 4 images; single input buffer ----
// 2 blocks/CU (LDS 80,896 B each) -> 12 waves/CU; staging of one block hides
// under the co-resident block's MFMA phase (inter-block overlap replaces dbuf).
#define EPILOG(ACC0, ACC1, RX, RY)                                                         \
    {                                                                                      \
        int pcolb = (RX) * 4 + 2 * hi;                                                     \
        _Pragma("unroll")                                                                  \
        for (int q = 0; q < 2; ++q) {                                                      \
            int prow = (RY) * 2 + q;                                                       \
            int bs = 8 * q;                                                                \
            float m00 = fmaxf(fmaxf(ACC0[bs], ACC0[bs + 1]), fmaxf(ACC0[bs + 4], ACC0[bs + 5])); \
            float m01 = fmaxf(fmaxf(ACC0[bs + 2], ACC0[bs + 3]), fmaxf(ACC0[bs + 6], ACC0[bs + 7])); \
            uint pk0 = (uint)f2bf(fmaxf(m00 + bias0, 0.f)) | ((uint)f2bf(fmaxf(m01 + bias0, 0.f)) << 16); \
            *(uint*)&pout[lo * 144 + prow * 12 + pcolb] = pk0;                             \
            float m10 = fmaxf(fmaxf(ACC1[bs], ACC1[bs + 1]), fmaxf(ACC1[bs + 4], ACC1[bs + 5])); \
            float m11 = fmaxf(fmaxf(ACC1[bs + 2], ACC1[bs + 3]), fmaxf(ACC1[bs + 6], ACC1[bs + 7])); \
            uint pk1 = (uint)f2bf(fmaxf(m10 + bias1, 0.f)) | ((uint)f2bf(fmaxf(m11 + bias1, 0.f)) << 16); \
            *(uint*)&pout[(lo + 32) * 144 + prow * 12 + pcolb] = pk1;                      \
        }                                                                                  \
    }

__global__ __launch_bounds__(384, 3) void conv2_persist(
    const ushort* __restrict__ h1b, const ushort* __restrict__ wt2,
    const float* __restrict__ c2b, ushort* __restrict__ pooled)
{
    __shared__ __attribute__((aligned(16))) ushort wt_lds[18432];   // [tap9][icg4][oc64][ic8]
    __shared__ __attribute__((aligned(16))) ushort in_lds[22016];   // [icg4][pix676][ic8] + pad
    int grp = blockIdx.x;             // 0..511, 4 images each
    int tid = threadIdx.x;
    int wave = tid >> 6;
    int lane = tid & 63;
    int lo = lane & 31;
    int hi = lane >> 5;

    // stage weights once (36 chunks)
    for (int c = wave; c < 36; c += 6) {
        const ushort* src = wt2 + (size_t)(c * 64 + lane) * 8;
        __builtin_amdgcn_global_load_lds(GLB_CP(src), LDS_CP(wt_lds + c * 512), 16, 0, 0);
    }
    float bias0 = c2b[lo];
    float bias1 = c2b[lo + 32];

    int pb[3];
#pragma unroll
    for (int i = 0; i < 3; ++i) {
        int r = wave + 6 * i;
        int rx = r % 3, ry = r / 3;
        int xcoord = rx * 8 + (lo & 7);
        int ycoord = ry * 4 + (lo >> 3);
        pb[i] = ycoord * 26 + xcoord;
    }
    int rx0 = wave % 3, ry0 = wave / 3;
    int rx1 = (wave + 6) % 3, ry1 = (wave + 6) / 3;
    int rx2 = (wave + 12) % 3, ry2 = (wave + 12) / 3;

    for (int j = 0; j < 4; ++j) {
        // stage this image (43 chunks); barrier drains weights too on j==0
        const ushort* base = h1b + (size_t)(grp * 4 + j) * 21632;
        for (int c = wave; c < 43; c += 6) {
            int e = c * 64 + lane;
            if (e > 2703) e = 2703;
            __builtin_amdgcn_global_load_lds(GLB_CP(base + (size_t)e * 8),
                                             LDS_CP(in_lds + c * 512), 16, 0, 0);
        }
        __syncthreads();

        f32x16 aA0 = (f32x16)0.f, aA1 = (f32x16)0.f;
        f32x16 aB0 = (f32x16)0.f, aB1 = (f32x16)0.f;
        f32x16 aC0 = (f32x16)0.f, aC1 = (f32x16)0.f;

#pragma unroll
        for (int tap = 0; tap < 9; ++tap) {
            int off = (tap / 3) * 26 + (tap % 3);
#pragma unroll
            for (int ks = 0; ks < 2; ++ks) {
                const ushort* wp = &wt_lds[((tap * 4 + ks * 2 + hi) * 64) * 8];
                short8 a0 = *(const short8*)(wp + lo * 8);
                short8 a1 = *(const short8*)(wp + (32 + lo) * 8);
                const ushort* ip = &in_lds[((ks * 2 + hi) * 676 + off) * 8];
                short8 b0 = *(const short8*)(ip + pb[0] * 8);
                short8 b1 = *(const short8*)(ip + pb[1] * 8);
                short8 b2 = *(const short8*)(ip + pb[2] * 8);
                aA0 = __builtin_amdgcn_mfma_f32_32x32x16_bf16(b0, a0, aA0, 0, 0, 0);
                aA1 = __builtin_amdgcn_mfma_f32_32x32x16_bf16(b0, a1, aA1, 0, 0, 0);
                aB0 = __builtin_amdgcn_mfma_f32_32x32x16_bf16(b1, a0, aB0, 0, 0, 0);
                aB1 = __builtin_amdgcn_mfma_f32_32x32x16_bf16(b1, a1, aB1, 0, 0, 0);
                aC0 = __builtin_amdgcn_mfma_f32_32x32x16_bf16(b2, a0, aC0, 0, 0, 0);
                aC1 = __builtin_amdgcn_mfma_f32_32x32x16_bf16(b2, a1, aC1, 0, 0, 0);
            }
        }

        ushort* pout = pooled + (size_t)(grp * 4 + j) * 9216;
        EPILOG(aA0, aA1, rx0, ry0)
        EPILOG(aB0, aB1, rx1, ry1)
        EPILOG(aC0, aC1, rx2, ry2)
        __syncthreads();   // all reads of in_lds done before next image's DMA
    }
}

// ---- fc1 MFMA: pooled[2048,9216]bf16 x wf1[128,9216]bf16^T, 4-way K-split ----
__global__ __launch_bounds__(256) void fc1_mfma(
    const ushort* __restrict__ pooled, const ushort* __restrict__ wf1,
    float* __restrict__ part)
{
    int bx = blockIdx.x, by = blockIdx.y;
    int tid = threadIdx.x;
    int wid = tid >> 6, lane = tid & 63;
    int lo = lane & 15, hi = lane >> 4;
    int m0 = bx * 32;
    int kb = by * 2304;

    f32x4 acc[2][2];
#pragma unroll
    for (int mt = 0; mt < 2; ++mt)
#pragma unroll
        for (int j = 0; j < 2; ++j) acc[mt][j] = (f32x4)0.f;

    const ushort* arow0 = pooled + (size_t)(m0 + lo) * 9216 + kb + hi * 8;
    const ushort* arow1 = arow0 + 16 * 9216;
    const ushort* brow0 = wf1 + (size_t)(wid * 32 + lo) * 9216 + kb + hi * 8;
    const ushort* brow1 = brow0 + 16 * 9216;

    for (int kt = 0; kt < 72; ++kt) {
        short8 a0 = *(const short8*)(arow0 + kt * 32);
        short8 a1 = *(const short8*)(arow1 + kt * 32);
        short8 b0 = *(const short8*)(brow0 + kt * 32);
        short8 b1 = *(const short8*)(brow1 + kt * 32);
        acc[0][0] = __builtin_amdgcn_mfma_f32_16x16x32_bf16(a0, b0, acc[0][0], 0, 0, 0);
        acc[1][0] = __builtin_amdgcn_mfma_f32_16x16x32_bf16(a1, b0, acc[1][0], 0, 0, 0);
        acc[0][1] = __builtin_amdgcn_mfma_f32_16x16x32_bf16(a0, b1, acc[0][1], 0, 0, 0);
        acc[1][1] = __builtin_amdgcn_mfma_f32_16x16x32_bf16(a1, b1, acc[1][1], 0, 0, 0);
    }
    float* pp = part + (size_t)by * 262144;
#pragma unroll
    for (int mt = 0; mt < 2; ++mt)
#pragma unroll
        for (int j = 0; j < 2; ++j)
#pragma unroll
            for (int r = 0; r < 4; ++r)
                pp[(m0 + mt * 16 + hi * 4 + r) * 128 + wid * 32 + j * 16 + lo] = acc[mt][j][r];
}

__global__ __launch_bounds__(256) void fc1_reduce_kernel(
    const float* __restrict__ part, const float* __restrict__ bias,
    float* __restrict__ outp)
{
    int idx = blockIdx.x * 256 + threadIdx.x;   // < 262144
    float s = 0.f;
#pragma unroll
    for (int ks = 0; ks < 4; ++ks) s += part[ks * 262144 + idx];
    outp[idx] = fmaxf(s + bias[idx & 127], 0.f);
}

// ---- fc2 + sigmoid*2pi -> angles[2048,10] (r11-proven) ----
__global__ __launch_bounds__(256) void fc2_kernel(
    const float* __restrict__ h, const float* __restrict__ w,
    const float* __restrict__ bias, float* __restrict__ ang)
{
    int idx = blockIdx.x * 256 + threadIdx.x;
    if (idx >= 20480) return;
    int b = idx / 10, n = idx % 10;
    const float* hp = h + b * 128;
    const float* wp = w + n * 128;
    float s = bias[n];
    for (int k = 0; k < 128; ++k) s = fmaf(hp[k], wp[k], s);
    ang[idx] = 6.28318530718f / (1.f + expf(-s));
}

// ---------------- quantum circuit (collapsed gate sequence, r13-proven) ----------------
__device__ __forceinline__ void apply_rot2(float2* s, int p, float2 m00, float2 m01,
                                           float2 m10, float2 m11, int tid)
{
    for (int q = tid; q < 512; q += 256) {
        int i0 = ((q >> p) << (p + 1)) | (q & ((1 << p) - 1));
        int i1 = i0 | (1 << p);
        float2 aa = s[i0], bb = s[i1];
        s[i0] = make_float2(m00.x * aa.x - m00.y * aa.y + m01.x * bb.x - m01.y * bb.y,
                            m00.x * aa.y + m00.y * aa.x + m01.x * bb.y + m01.y * bb.x);
        s[i1] = make_float2(m10.x * aa.x - m10.y * aa.y + m11.x * bb.x - m11.y * bb.y,
                            m10.x * aa.y + m10.y * aa.x + m11.x * bb.y + m11.y * bb.x);
    }
}

__global__ __launch_bounds__(256) void quantum_kernel(
    const float* __restrict__ ang, const float* __restrict__ theta0,
    const float* __restrict__ theta_rz, const float* __restrict__ theta_ps,
    const float* __restrict__ rot_p, float* __restrict__ out)
{
    __shared__ float2 s[1024];
    __shared__ float red[40];
    __shared__ float P[64];
    int b = blockIdx.x;
    int tid = threadIdx.x;

    if (tid < 13) {
        if (tid < 10) {
            int k = tid;
            float ak = ang[b * 10 + k];
            float th = theta0[k] + ak;
            if (k == 1) th += ak;
            if (k == 5) th -= 0.78539816339745f;
            float c, sn; sincosf(0.5f * th, &sn, &c);
            float2 v0 = make_float2(c, 0.f), v1 = make_float2(0.f, -sn);
            if (k == 0) v1 = make_float2(-sn, 0.f);
            if (k == 2) { float ca, sa; sincosf(0.5f * ak, &sa, &ca);
                float2 n0 = make_float2(ca * v0.x - sa * v1.x, ca * v0.y - sa * v1.y);
                float2 n1 = make_float2(sa * v0.x + ca * v1.x, sa * v0.y + ca * v1.y);
                v0 = n0; v1 = n1; }
            if (k == 3) { float ca, sa; sincosf(0.5f * ak, &sa, &ca);
                v0 = cmul(v0, make_float2(ca, -sa));
                v1 = cmul(v1, make_float2(ca, sa)); }
            if (k == 4) { float2 t = v1; v1 = make_float2(-t.y, t.x); }
            if (k == 5) { const float r = 0.70710678118655f;
                float2 t = v1; v1 = make_float2(r * (t.x - t.y), r * (t.x + t.y)); }
            if (k == 6) { float ca, sa; sincosf(0.5f * theta_rz[0], &sa, &ca);
                v0 = cmul(v0, make_float2(ca, -sa));
                v1 = cmul(v1, make_float2(ca, sa)); }
            if (k == 7) { float2 p = v0, q = v1;
                v0 = make_float2(0.5f * ((p.x - p.y) + (q.x + q.y)),
                                 0.5f * ((p.x + p.y) + (q.y - q.x)));
                v1 = make_float2(0.5f * ((p.x + p.y) + (q.x - q.y)),
                                 0.5f * ((p.y - p.x) + (q.x + q.y)));
                float c2, s2; sincosf(ak, &s2, &c2);
                v1 = cmul(v1, make_float2(c2, s2)); }
            P[k * 4 + 0] = v0.x; P[k * 4 + 1] = v0.y;
            P[k * 4 + 2] = v1.x; P[k * 4 + 3] = v1.y;
        } else if (tid == 10) {
            float c1, s1; sincosf(theta_ps[0], &s1, &c1);
            P[40] = c1; P[41] = s1;
        } else if (tid == 11) {
            float c, sn; sincosf(0.5f * rot_p[1], &sn, &c);
            float A = 0.5f * (rot_p[0] + rot_p[2]), Bv = 0.5f * (rot_p[0] - rot_p[2]);
            float cA, sA; sincosf(A, &sA, &cA);
            float cB, sB; sincosf(Bv, &sB, &cB);
            P[44] = cA * c;  P[45] = -sA * c;
            P[46] = -cB * sn; P[47] = -sB * sn;
            P[48] = cB * sn;  P[49] = -sB * sn;
            P[50] = cA * c;  P[51] = sA * c;
        } else {
            float a6 = ang[b * 10 + 6], a7 = ang[b * 10 + 7], a8 = ang[b * 10 + 8];
            float c, sn; sincosf(0.5f * a7, &sn, &c);
            float A = 0.5f * (a6 + a8), Bv = 0.5f * (a6 - a8);
            float cA, sA; sincosf(A, &sA, &cA);
            float cB, sB; sincosf(Bv, &sB, &cB);
            P[52] = cA * c;  P[53] = -sA * c;
            P[54] = -cB * sn; P[55] = -sB * sn;
            P[56] = cB * sn;  P[57] = -sB * sn;
            P[58] = cA * c;  P[59] = sA * c;
        }
    }
    __syncthreads();

    float2 v[10][2];
#pragma unroll
    for (int k = 0; k < 10; ++k) {
        int slot = (k == 2) ? 3 : (k == 3) ? 2 : k;
        v[k][0] = make_float2(P[slot * 4], P[slot * 4 + 1]);
        v[k][1] = make_float2(P[slot * 4 + 2], P[slot * 4 + 3]);
    }

    for (int i = tid; i < 1024; i += 256) {
        float2 c = ((i >> 9) & 1) ? v[0][1] : v[0][0];
#pragma unroll
        for (int k = 1; k < 10; ++k) {
            float2 vk = ((i >> (9 - k)) & 1) ? v[k][1] : v[k][0];
            c = cmul(c, vk);
        }
        s[i] = c;
    }
    __syncthreads();

    { // CY(ctrl bit7, tgt bit1) + Phase(theta_ps) on bit1
        int j = tid;
        float2 p1 = make_float2(P[40], P[41]);
        int i0 = (j & 1) | (((j >> 1) & 31) << 2) | (((j >> 6) & 3) << 8) | 128;
        int i1 = i0 | 2;
        float2 t0 = s[i0], t1 = s[i1];
        s[i0] = make_float2(t1.y, -t1.x);
        s[i1] = cmul(make_float2(-t0.y, t0.x), p1);
        int i2 = (j & 1) | 2 | (((j >> 1) & 31) << 2) | (((j >> 6) & 3) << 8);
        s[i2] = cmul(s[i2], p1);
    }
    __syncthreads();
    if (tid < 128) {
        int j = tid;
        int i0 = (j & 7) | 16 | 32 | (((j >> 3) & 15) << 6);
        int i1 = i0 ^ 0x18;
        float2 t0 = s[i0], t1 = s[i1];
        s[i0] = t1; s[i1] = t0;
    }
    __syncthreads();
    if (tid < 128) {
        int j = tid;
        int i0 = (j & 1) | 2 | (((j >> 1) & 3) << 2) | 16 | (((j >> 3) & 15) << 5);
        int i1 = i0 | 512;
        float2 t0 = s[i0], t1 = s[i1];
        s[i0] = t1; s[i1] = t0;
    }
    __syncthreads();
    apply_rot2(s, 5, make_float2(P[44], P[45]), make_float2(P[46], P[47]),
               make_float2(P[48], P[49]), make_float2(P[50], P[51]), tid);
    __syncthreads();
    apply_rot2(s, 4, make_float2(P[52], P[53]), make_float2(P[54], P[55]),
               make_float2(P[56], P[57]), make_float2(P[58], P[59]), tid);
    __syncthreads();

    int wave = tid >> 6;
    for (int k = 0; k < 10; ++k) {
        int p = 9 - k;
        float part = 0.f;
        for (int q = tid; q < 512; q += 256) {
            int i0 = ((q >> p) << (p + 1)) | (q & ((1 << p) - 1));
            int i1 = i0 | (1 << p);
            float2 aa = s[i0], bb = s[i1];
            part += aa.x * bb.y - aa.y * bb.x;
        }
        part *= 2.f;
#pragma unroll
        for (int off = 32; off > 0; off >>= 1)
            part += __shfl_down(part, off, 64);
        if ((tid & 63) == 0) red[k * 4 + wave] = part;
    }
    __syncthreads();
    if (tid == 0) {
        float ev[10];
        float mx = -1e30f;
#pragma unroll
        for (int k = 0; k < 10; ++k) {
            ev[k] = red[k * 4] + red[k * 4 + 1] + red[k * 4 + 2] + red[k * 4 + 3];
            mx = fmaxf(mx, ev[k]);
        }
        float sum = 0.f;
#pragma unroll
        for (int k = 0; k < 10; ++k) sum += expf(ev[k] - mx);
        float lse = mx + logf(sum);
#pragma unroll
        for (int k = 0; k < 10; ++k) out[b * 10 + k] = ev[k] - lse;
    }
}

extern "C" void kernel_launch(void* const* d_in, const int* in_sizes, int n_in,
                              void* d_out, int out_size, void* d_ws, size_t ws_size,
                              hipStream_t stream)
{
    (void)in_sizes; (void)n_in; (void)out_size; (void)ws_size;
    const float* x    = (const float*)d_in[0];
    const float* c1w  = (const float*)d_in[1];
    const float* c1b  = (const float*)d_in[2];
    const float* c2w  = (const float*)d_in[3];
    const float* c2b  = (const float*)d_in[4];
    const float* f1w  = (const float*)d_in[5];
    const float* f1b  = (const float*)d_in[6];
    const float* f2w  = (const float*)d_in[7];
    const float* f2b  = (const float*)d_in[8];
    const float* th0  = (const float*)d_in[9];
    const float* trz  = (const float*)d_in[10];
    const float* tps  = (const float*)d_in[11];
    const float* rotp = (const float*)d_in[12];
    float* out = (float*)d_out;

    char* ws = (char*)d_ws;
    ushort* h1b    = (ushort*)(ws);                       // 88,604,672 B
    ushort* pooled = (ushort*)(ws + 88604672);            // 37,748,736 B
    ushort* wt2    = (ushort*)(ws + 126353408);           //     36,864 B
    ushort* wf1    = (ushort*)(ws + 126390272);           //  2,359,296 B
    float*  part   = (float*)(ws + 128749568);            //  4,194,304 B
    float*  fc1o   = (float*)(ws + 132943872);            //  1,048,576 B
    float*  ang    = (float*)(ws + 133992448);            //     81,920 B

    prep_kernel<<<4680, 256, 0, stream>>>(c2w, f1w, wt2, wf1);
    conv1_kernel<<<21632, 256, 0, stream>>>(x, c1w, c1b, h1b);
    conv2_persist<<<512, 384, 0, stream>>>(h1b, wt2, c2b, pooled);
    fc1_mfma<<<dim3(64, 4), 256, 0, stream>>>(pooled, wf1, part);
    fc1_reduce_kernel<<<1024, 256, 0, stream>>>(part, f1b, fc1o);
    fc2_kernel<<<80, 256, 0, stream>>>(fc1o, f2w, f2b, ang);
    quantum_kernel<<<2048, 256, 0, stream>>>(ang, th0, trz, tps, rotp, out);
}

// Round 15
// 151.278 us; speedup vs baseline: 1.0899x; 1.0899x over previous
//
#include <hip/hip_runtime.h>
#include <math.h>

typedef short short8 __attribute__((ext_vector_type(8)));
typedef float f32x4 __attribute__((ext_vector_type(4)));
typedef float f32x16 __attribute__((ext_vector_type(16)));

#define GLB_CP(p) ((const __attribute__((address_space(1))) void*)(p))
#define LDS_CP(p) ((__attribute__((address_space(3))) void*)(p))

__device__ __forceinline__ float2 cmul(float2 a, float2 b) {
    return make_float2(a.x * b.x - a.y * b.y, a.x * b.y + a.y * b.x);
}

__device__ __forceinline__ ushort f2bf(float f) {
    uint u = __float_as_uint(f);
    uint r = (u + 0x7FFFu + ((u >> 16) & 1u)) >> 16;
    return (ushort)r;
}

// ---- prep: conv2 weights -> wt2[tap][icg][oc][ic8] bf16 ; fc1 weights -> bf16 ----
__global__ __launch_bounds__(256) void prep_kernel(
    const float* __restrict__ c2w, const float* __restrict__ f1w,
    ushort* __restrict__ wt2, ushort* __restrict__ wf1)
{
    int i = blockIdx.x * 256 + threadIdx.x;
    if (i < 18432) {
        int icl = i & 7;
        int t = i >> 3;
        int oc = t & 63;
        int t2 = t >> 6;
        int icg = t2 & 3;
        int tap = t2 >> 2;
        int ic = icg * 8 + icl;
        wt2[i] = f2bf(c2w[(oc * 32 + ic) * 9 + tap]);
    } else if (i < 18432 + 1179648) {
        int j = i - 18432;
        wf1[j] = f2bf(f1w[j]);
    }
}

// ---- conv1 + relu -> h1b[b][icg][pix][ic8] bf16 (fully parallel, r3-proven) ----
__global__ __launch_bounds__(256) void conv1_kernel(
    const float* __restrict__ x, const float* __restrict__ w1,
    const float* __restrict__ b1, ushort* __restrict__ h1b)
{
    __shared__ float wl[288];
    __shared__ float bl[32];
    int tid = threadIdx.x;
    for (int e = tid; e < 288; e += 256) wl[e] = w1[e];
    if (tid < 32) bl[tid] = b1[tid];
    __syncthreads();
    int e = blockIdx.x * 256 + tid;          // 2048*676*4 total, exact grid
    int icg = e & 3;
    int t = e >> 2;
    int pix = t % 676;
    int b = t / 676;
    int y = pix / 26, xc = pix % 26;
    const float* xp = x + b * 784 + y * 28 + xc;
    float in9[9];
#pragma unroll
    for (int ky = 0; ky < 3; ++ky)
#pragma unroll
        for (int kx = 0; kx < 3; ++kx) in9[ky * 3 + kx] = xp[ky * 28 + kx];
    short8 outv;
#pragma unroll
    for (int o = 0; o < 8; ++o) {
        int oc = icg * 8 + o;
        float acc = bl[oc];
#pragma unroll
        for (int k = 0; k < 9; ++k) acc = fmaf(in9[k], wl[oc * 9 + k], acc);
        outv[o] = (short)f2bf(fmaxf(acc, 0.f));
    }
    *(short8*)&h1b[((b * 4 + icg) * 676 + pix) * 8] = outv;
}

// ---- conv2 persistent (r13-proven structure): 256 blocks x 8 images, dbuf ----
// + A-fragment register hoist: oc-half-0 weight frags (18 short8) cached across
//   the image loop -> 72 instead of 90 ds_read_b128 per wave per image.
#define EPILOG(ACC0, ACC1, RX, RY)                                                         \
    {                                                                                      \
        int pcolb = (RX) * 4 + 2 * hi;                                                     \
        _Pragma("unroll")                                                                  \
        for (int q = 0; q < 2; ++q) {                                                      \
            int prow = (RY) * 2 + q;                                                       \
            int bs = 8 * q;                                                                \
            float m00 = fmaxf(fmaxf(ACC0[bs], ACC0[bs + 1]), fmaxf(ACC0[bs + 4], ACC0[bs + 5])); \
            float m01 = fmaxf(fmaxf(ACC0[bs + 2], ACC0[bs + 3]), fmaxf(ACC0[bs + 6], ACC0[bs + 7])); \
            uint pk0 = (uint)f2bf(fmaxf(m00 + bias0, 0.f)) | ((uint)f2bf(fmaxf(m01 + bias0, 0.f)) << 16); \
            *(uint*)&pout[lo * 144 + prow * 12 + pcolb] = pk0;                             \
            float m10 = fmaxf(fmaxf(ACC1[bs], ACC1[bs + 1]), fmaxf(ACC1[bs + 4], ACC1[bs + 5])); \
            float m11 = fmaxf(fmaxf(ACC1[bs + 2], ACC1[bs + 3]), fmaxf(ACC1[bs + 6], ACC1[bs + 7])); \
            uint pk1 = (uint)f2bf(fmaxf(m10 + bias1, 0.f)) | ((uint)f2bf(fmaxf(m11 + bias1, 0.f)) << 16); \
            *(uint*)&pout[(lo + 32) * 144 + prow * 12 + pcolb] = pk1;                      \
        }                                                                                  \
    }

__global__ __launch_bounds__(384, 2) void conv2_persist(
    const ushort* __restrict__ h1b, const ushort* __restrict__ wt2,
    const float* __restrict__ c2b, ushort* __restrict__ pooled)
{
    __shared__ __attribute__((aligned(16))) ushort wt_lds[18432];     // [tap9][icg4][oc64][ic8]
    __shared__ __attribute__((aligned(16))) ushort in_lds[2][22016];  // [icg4][pix676][ic8] + pad
    int cu = blockIdx.x;              // 0..255, 8 images each
    int tid = threadIdx.x;
    int wave = tid >> 6;
    int lane = tid & 63;
    int lo = lane & 31;
    int hi = lane >> 5;

    for (int c = wave; c < 36; c += 6) {
        const ushort* src = wt2 + (size_t)(c * 64 + lane) * 8;
        __builtin_amdgcn_global_load_lds(GLB_CP(src), LDS_CP(wt_lds + c * 512), 16, 0, 0);
    }
    {
        const ushort* base = h1b + (size_t)(cu * 8) * 21632;
        for (int c = wave; c < 43; c += 6) {
            int e = c * 64 + lane;
            if (e > 2703) e = 2703;
            __builtin_amdgcn_global_load_lds(GLB_CP(base + (size_t)e * 8),
                                             LDS_CP(in_lds[0] + c * 512), 16, 0, 0);
        }
    }
    float bias0 = c2b[lo];
    float bias1 = c2b[lo + 32];
    __syncthreads();

    // hoist oc-half-0 weight fragments into registers (image-invariant)
    short8 A0r[9][2];
#pragma unroll
    for (int tap = 0; tap < 9; ++tap)
#pragma unroll
        for (int ks = 0; ks < 2; ++ks)
            A0r[tap][ks] = *(const short8*)&wt_lds[((tap * 4 + ks * 2 + hi) * 64 + lo) * 8];

    int pb[3];
#pragma unroll
    for (int i = 0; i < 3; ++i) {
        int r = wave + 6 * i;
        int rx = r % 3, ry = r / 3;
        int xcoord = rx * 8 + (lo & 7);
        int ycoord = ry * 4 + (lo >> 3);
        pb[i] = ycoord * 26 + xcoord;
    }
    int rx0 = wave % 3, ry0 = wave / 3;
    int rx1 = (wave + 6) % 3, ry1 = (wave + 6) / 3;
    int rx2 = (wave + 12) % 3, ry2 = (wave + 12) / 3;

    for (int j = 0; j < 8; ++j) {
        if (j < 7) {
            const ushort* base = h1b + (size_t)(cu * 8 + j + 1) * 21632;
            ushort* dst = in_lds[(j + 1) & 1];
            for (int c = wave; c < 43; c += 6) {
                int e = c * 64 + lane;
                if (e > 2703) e = 2703;
                __builtin_amdgcn_global_load_lds(GLB_CP(base + (size_t)e * 8),
                                                 LDS_CP(dst + c * 512), 16, 0, 0);
            }
        }

        const ushort* ib = in_lds[j & 1];
        f32x16 aA0 = (f32x16)0.f, aA1 = (f32x16)0.f;
        f32x16 aB0 = (f32x16)0.f, aB1 = (f32x16)0.f;
        f32x16 aC0 = (f32x16)0.f, aC1 = (f32x16)0.f;

#pragma unroll
        for (int tap = 0; tap < 9; ++tap) {
            int off = (tap / 3) * 26 + (tap % 3);
#pragma unroll
            for (int ks = 0; ks < 2; ++ks) {
                short8 a0 = A0r[tap][ks];
                short8 a1 = *(const short8*)&wt_lds[((tap * 4 + ks * 2 + hi) * 64 + 32 + lo) * 8];
                const ushort* ip = &ib[((ks * 2 + hi) * 676 + off) * 8];
                short8 b0 = *(const short8*)(ip + pb[0] * 8);
                short8 b1 = *(const short8*)(ip + pb[1] * 8);
                short8 b2 = *(const short8*)(ip + pb[2] * 8);
                aA0 = __builtin_amdgcn_mfma_f32_32x32x16_bf16(b0, a0, aA0, 0, 0, 0);
                aA1 = __builtin_amdgcn_mfma_f32_32x32x16_bf16(b0, a1, aA1, 0, 0, 0);
                aB0 = __builtin_amdgcn_mfma_f32_32x32x16_bf16(b1, a0, aB0, 0, 0, 0);
                aB1 = __builtin_amdgcn_mfma_f32_32x32x16_bf16(b1, a1, aB1, 0, 0, 0);
                aC0 = __builtin_amdgcn_mfma_f32_32x32x16_bf16(b2, a0, aC0, 0, 0, 0);
                aC1 = __builtin_amdgcn_mfma_f32_32x32x16_bf16(b2, a1, aC1, 0, 0, 0);
            }
        }

        ushort* pout = pooled + (size_t)(cu * 8 + j) * 9216;
        EPILOG(aA0, aA1, rx0, ry0)
        EPILOG(aB0, aB1, rx1, ry1)
        EPILOG(aC0, aC1, rx2, ry2)
        __syncthreads();
    }
}

// ---- fc1 MFMA: pooled[2048,9216]bf16 x wf1[128,9216]bf16^T, 4-way K-split ----
__global__ __launch_bounds__(256) void fc1_mfma(
    const ushort* __restrict__ pooled, const ushort* __restrict__ wf1,
    float* __restrict__ part)
{
    int bx = blockIdx.x, by = blockIdx.y;
    int tid = threadIdx.x;
    int wid = tid >> 6, lane = tid & 63;
    int lo = lane & 15, hi = lane >> 4;
    int m0 = bx * 32;
    int kb = by * 2304;

    f32x4 acc[2][2];
#pragma unroll
    for (int mt = 0; mt < 2; ++mt)
#pragma unroll
        for (int j = 0; j < 2; ++j) acc[mt][j] = (f32x4)0.f;

    const ushort* arow0 = pooled + (size_t)(m0 + lo) * 9216 + kb + hi * 8;
    const ushort* arow1 = arow0 + 16 * 9216;
    const ushort* brow0 = wf1 + (size_t)(wid * 32 + lo) * 9216 + kb + hi * 8;
    const ushort* brow1 = brow0 + 16 * 9216;

    for (int kt = 0; kt < 72; ++kt) {
        short8 a0 = *(const short8*)(arow0 + kt * 32);
        short8 a1 = *(const short8*)(arow1 + kt * 32);
        short8 b0 = *(const short8*)(brow0 + kt * 32);
        short8 b1 = *(const short8*)(brow1 + kt * 32);
        acc[0][0] = __builtin_amdgcn_mfma_f32_16x16x32_bf16(a0, b0, acc[0][0], 0, 0, 0);
        acc[1][0] = __builtin_amdgcn_mfma_f32_16x16x32_bf16(a1, b0, acc[1][0], 0, 0, 0);
        acc[0][1] = __builtin_amdgcn_mfma_f32_16x16x32_bf16(a0, b1, acc[0][1], 0, 0, 0);
        acc[1][1] = __builtin_amdgcn_mfma_f32_16x16x32_bf16(a1, b1, acc[1][1], 0, 0, 0);
    }
    float* pp = part + (size_t)by * 262144;
#pragma unroll
    for (int mt = 0; mt < 2; ++mt)
#pragma unroll
        for (int j = 0; j < 2; ++j)
#pragma unroll
            for (int r = 0; r < 4; ++r)
                pp[(m0 + mt * 16 + hi * 4 + r) * 128 + wid * 32 + j * 16 + lo] = acc[mt][j][r];
}

__global__ __launch_bounds__(256) void fc1_reduce_kernel(
    const float* __restrict__ part, const float* __restrict__ bias,
    float* __restrict__ outp)
{
    int idx = blockIdx.x * 256 + threadIdx.x;   // < 262144
    float s = 0.f;
#pragma unroll
    for (int ks = 0; ks < 4; ++ks) s += part[ks * 262144 + idx];
    outp[idx] = fmaxf(s + bias[idx & 127], 0.f);
}

// ---- fc2 + sigmoid*2pi -> angles[2048,10] (r11-proven) ----
__global__ __launch_bounds__(256) void fc2_kernel(
    const float* __restrict__ h, const float* __restrict__ w,
    const float* __restrict__ bias, float* __restrict__ ang)
{
    int idx = blockIdx.x * 256 + threadIdx.x;
    if (idx >= 20480) return;
    int b = idx / 10, n = idx % 10;
    const float* hp = h + b * 128;
    const float* wp = w + n * 128;
    float s = bias[n];
    for (int k = 0; k < 128; ++k) s = fmaf(hp[k], wp[k], s);
    ang[idx] = 6.28318530718f / (1.f + expf(-s));
}

// ---------------- quantum circuit (collapsed gate sequence, r13-proven) ----------------
__device__ __forceinline__ void apply_rot2(float2* s, int p, float2 m00, float2 m01,
                                           float2 m10, float2 m11, int tid)
{
    for (int q = tid; q < 512; q += 256) {
        int i0 = ((q >> p) << (p + 1)) | (q & ((1 << p) - 1));
        int i1 = i0 | (1 << p);
        float2 aa = s[i0], bb = s[i1];
        s[i0] = make_float2(m00.x * aa.x - m00.y * aa.y + m01.x * bb.x - m01.y * bb.y,
                            m00.x * aa.y + m00.y * aa.x + m01.x * bb.y + m01.y * bb.x);
        s[i1] = make_float2(m10.x * aa.x - m10.y * aa.y + m11.x * bb.x - m11.y * bb.y,
                            m10.x * aa.y + m10.y * aa.x + m11.x * bb.y + m11.y * bb.x);
    }
}

__global__ __launch_bounds__(256) void quantum_kernel(
    const float* __restrict__ ang, const float* __restrict__ theta0,
    const float* __restrict__ theta_rz, const float* __restrict__ theta_ps,
    const float* __restrict__ rot_p, float* __restrict__ out)
{
    __shared__ float2 s[1024];
    __shared__ float red[40];
    __shared__ float P[64];
    int b = blockIdx.x;
    int tid = threadIdx.x;

    if (tid < 13) {
        if (tid < 10) {
            int k = tid;
            float ak = ang[b * 10 + k];
            float th = theta0[k] + ak;
            if (k == 1) th += ak;
            if (k == 5) th -= 0.78539816339745f;
            float c, sn; sincosf(0.5f * th, &sn, &c);
            float2 v0 = make_float2(c, 0.f), v1 = make_float2(0.f, -sn);
            if (k == 0) v1 = make_float2(-sn, 0.f);
            if (k == 2) { float ca, sa; sincosf(0.5f * ak, &sa, &ca);
                float2 n0 = make_float2(ca * v0.x - sa * v1.x, ca * v0.y - sa * v1.y);
                float2 n1 = make_float2(sa * v0.x + ca * v1.x, sa * v0.y + ca * v1.y);
                v0 = n0; v1 = n1; }
            if (k == 3) { float ca, sa; sincosf(0.5f * ak, &sa, &ca);
                v0 = cmul(v0, make_float2(ca, -sa));
                v1 = cmul(v1, make_float2(ca, sa)); }
            if (k == 4) { float2 t = v1; v1 = make_float2(-t.y, t.x); }
            if (k == 5) { const float r = 0.70710678118655f;
                float2 t = v1; v1 = make_float2(r * (t.x - t.y), r * (t.x + t.y)); }
            if (k == 6) { float ca, sa; sincosf(0.5f * theta_rz[0], &sa, &ca);
                v0 = cmul(v0, make_float2(ca, -sa));
                v1 = cmul(v1, make_float2(ca, sa)); }
            if (k == 7) { float2 p = v0, q = v1;
                v0 = make_float2(0.5f * ((p.x - p.y) + (q.x + q.y)),
                                 0.5f * ((p.x + p.y) + (q.y - q.x)));
                v1 = make_float2(0.5f * ((p.x + p.y) + (q.x - q.y)),
                                 0.5f * ((p.y - p.x) + (q.x + q.y)));
                float c2, s2; sincosf(ak, &s2, &c2);
                v1 = cmul(v1, make_float2(c2, s2)); }
            P[k * 4 + 0] = v0.x; P[k * 4 + 1] = v0.y;
            P[k * 4 + 2] = v1.x; P[k * 4 + 3] = v1.y;
        } else if (tid == 10) {
            float c1, s1; sincosf(theta_ps[0], &s1, &c1);
            P[40] = c1; P[41] = s1;
        } else if (tid == 11) {
            float c, sn; sincosf(0.5f * rot_p[1], &sn, &c);
            float A = 0.5f * (rot_p[0] + rot_p[2]), Bv = 0.5f * (rot_p[0] - rot_p[2]);
            float cA, sA; sincosf(A, &sA, &cA);
            float cB, sB; sincosf(Bv, &sB, &cB);
            P[44] = cA * c;  P[45] = -sA * c;
            P[46] = -cB * sn; P[47] = -sB * sn;
            P[48] = cB * sn;  P[49] = -sB * sn;
            P[50] = cA * c;  P[51] = sA * c;
        } else {
            float a6 = ang[b * 10 + 6], a7 = ang[b * 10 + 7], a8 = ang[b * 10 + 8];
            float c, sn; sincosf(0.5f * a7, &sn, &c);
            float A = 0.5f * (a6 + a8), Bv = 0.5f * (a6 - a8);
            float cA, sA; sincosf(A, &sA, &cA);
            float cB, sB; sincosf(Bv, &sB, &cB);
            P[52] = cA * c;  P[53] = -sA * c;
            P[54] = -cB * sn; P[55] = -sB * sn;
            P[56] = cB * sn;  P[57] = -sB * sn;
            P[58] = cA * c;  P[59] = sA * c;
        }
    }
    __syncthreads();

    float2 v[10][2];
#pragma unroll
    for (int k = 0; k < 10; ++k) {
        int slot = (k == 2) ? 3 : (k == 3) ? 2 : k;
        v[k][0] = make_float2(P[slot * 4], P[slot * 4 + 1]);
        v[k][1] = make_float2(P[slot * 4 + 2], P[slot * 4 + 3]);
    }

    for (int i = tid; i < 1024; i += 256) {
        float2 c = ((i >> 9) & 1) ? v[0][1] : v[0][0];
#pragma unroll
        for (int k = 1; k < 10; ++k) {
            float2 vk = ((i >> (9 - k)) & 1) ? v[k][1] : v[k][0];
            c = cmul(c, vk);
        }
        s[i] = c;
    }
    __syncthreads();

    { // CY(ctrl bit7, tgt bit1) + Phase(theta_ps) on bit1
        int j = tid;
        float2 p1 = make_float2(P[40], P[41]);
        int i0 = (j & 1) | (((j >> 1) & 31) << 2) | (((j >> 6) & 3) << 8) | 128;
        int i1 = i0 | 2;
        float2 t0 = s[i0], t1 = s[i1];
        s[i0] = make_float2(t1.y, -t1.x);
        s[i1] = cmul(make_float2(-t0.y, t0.x), p1);
        int i2 = (j & 1) | 2 | (((j >> 1) & 31) << 2) | (((j >> 6) & 3) << 8);
        s[i2] = cmul(s[i2], p1);
    }
    __syncthreads();
    if (tid < 128) {
        int j = tid;
        int i0 = (j & 7) | 16 | 32 | (((j >> 3) & 15) << 6);
        int i1 = i0 ^ 0x18;
        float2 t0 = s[i0], t1 = s[i1];
        s[i0] = t1; s[i1] = t0;
    }
    __syncthreads();
    if (tid < 128) {
        int j = tid;
        int i0 = (j & 1) | 2 | (((j >> 1) & 3) << 2) | 16 | (((j >> 3) & 15) << 5);
        int i1 = i0 | 512;
        float2 t0 = s[i0], t1 = s[i1];
        s[i0] = t1; s[i1] = t0;
    }
    __syncthreads();
    apply_rot2(s, 5, make_float2(P[44], P[45]), make_float2(P[46], P[47]),
               make_float2(P[48], P[49]), make_float2(P[50], P[51]), tid);
    __syncthreads();
    apply_rot2(s, 4, make_float2(P[52], P[53]), make_float2(P[54], P[55]),
               make_float2(P[56], P[57]), make_float2(P[58], P[59]), tid);
    __syncthreads();

    int wave = tid >> 6;
    for (int k = 0; k < 10; ++k) {
        int p = 9 - k;
        float part = 0.f;
        for (int q = tid; q < 512; q += 256) {
            int i0 = ((q >> p) << (p + 1)) | (q & ((1 << p) - 1));
            int i1 = i0 | (1 << p);
            float2 aa = s[i0], bb = s[i1];
            part += aa.x * bb.y - aa.y * bb.x;
        }
        part *= 2.f;
#pragma unroll
        for (int off = 32; off > 0; off >>= 1)
            part += __shfl_down(part, off, 64);
        if ((tid & 63) == 0) red[k * 4 + wave] = part;
    }
    __syncthreads();
    if (tid == 0) {
        float ev[10];
        float mx = -1e30f;
#pragma unroll
        for (int k = 0; k < 10; ++k) {
            ev[k] = red[k * 4] + red[k * 4 + 1] + red[k * 4 + 2] + red[k * 4 + 3];
            mx = fmaxf(mx, ev[k]);
        }
        float sum = 0.f;
#pragma unroll
        for (int k = 0; k < 10; ++k) sum += expf(ev[k] - mx);
        float lse = mx + logf(sum);
#pragma unroll
        for (int k = 0; k < 10; ++k) out[b * 10 + k] = ev[k] - lse;
    }
}

extern "C" void kernel_launch(void* const* d_in, const int* in_sizes, int n_in,
                              void* d_out, int out_size, void* d_ws, size_t ws_size,
                              hipStream_t stream)
{
    (void)in_sizes; (void)n_in; (void)out_size; (void)ws_size;
    const float* x    = (const float*)d_in[0];
    const float* c1w  = (const float*)d_in[1];
    const float* c1b  = (const float*)d_in[2];
    const float* c2w  = (const float*)d_in[3];
    const float* c2b  = (const float*)d_in[4];
    const float* f1w  = (const float*)d_in[5];
    const float* f1b  = (const float*)d_in[6];
    const float* f2w  = (const float*)d_in[7];
    const float* f2b  = (const float*)d_in[8];
    const float* th0  = (const float*)d_in[9];
    const float* trz  = (const float*)d_in[10];
    const float* tps  = (const float*)d_in[11];
    const float* rotp = (const float*)d_in[12];
    float* out = (float*)d_out;

    char* ws = (char*)d_ws;
    ushort* h1b    = (ushort*)(ws);                       // 88,604,672 B
    ushort* pooled = (ushort*)(ws + 88604672);            // 37,748,736 B
    ushort* wt2    = (ushort*)(ws + 126353408);           //     36,864 B
    ushort* wf1    = (ushort*)(ws + 126390272);           //  2,359,296 B
    float*  part   = (float*)(ws + 128749568);            //  4,194,304 B
    float*  fc1o   = (float*)(ws + 132943872);            //  1,048,576 B
    float*  ang    = (float*)(ws + 133992448);            //     81,920 B

    prep_kernel<<<4680, 256, 0, stream>>>(c2w, f1w, wt2, wf1);
    conv1_kernel<<<21632, 256, 0, stream>>>(x, c1w, c1b, h1b);
    conv2_persist<<<256, 384, 0, stream>>>(h1b, wt2, c2b, pooled);
    fc1_mfma<<<dim3(64, 4), 256, 0, stream>>>(pooled, wf1, part);
    fc1_reduce_kernel<<<1024, 256, 0, stream>>>(part, f1b, fc1o);
    fc2_kernel<<<80, 256, 0, stream>>>(fc1o, f2w, f2b, ang);
    quantum_kernel<<<2048, 256, 0, stream>>>(ang, th0, trz, tps, rotp, out);
}

// Round 16
// 140.544 us; speedup vs baseline: 1.1732x; 1.0764x over previous
//
#include <hip/hip_runtime.h>
#include <math.h>

typedef short short8 __attribute__((ext_vector_type(8)));
typedef float f32x4 __attribute__((ext_vector_type(4)));
typedef float f32x16 __attribute__((ext_vector_type(16)));

#define GLB_CP(p) ((const __attribute__((address_space(1))) void*)(p))
#define LDS_CP(p) ((__attribute__((address_space(3))) void*)(p))

__device__ __forceinline__ float2 cmul(float2 a, float2 b) {
    return make_float2(a.x * b.x - a.y * b.y, a.x * b.y + a.y * b.x);
}

__device__ __forceinline__ ushort f2bf(float f) {
    uint u = __float_as_uint(f);
    uint r = (u + 0x7FFFu + ((u >> 16) & 1u)) >> 16;
    return (ushort)r;
}

// ---- merged conv1+prep: blocks [0,21632) conv1; blocks [21632,26312) weight prep ----
__global__ __launch_bounds__(256) void conv1_prep_kernel(
    const float* __restrict__ x, const float* __restrict__ w1,
    const float* __restrict__ b1, ushort* __restrict__ h1b,
    const float* __restrict__ c2w, const float* __restrict__ f1w,
    ushort* __restrict__ wt2, ushort* __restrict__ wf1)
{
    __shared__ float wl[288];
    __shared__ float bl[32];
    int blk = blockIdx.x;
    int tid = threadIdx.x;
    if (blk >= 21632) {           // prep branch (whole block uniform)
        int i = (blk - 21632) * 256 + tid;
        if (i < 18432) {
            int icl = i & 7;
            int t = i >> 3;
            int oc = t & 63;
            int t2 = t >> 6;
            int icg = t2 & 3;
            int tap = t2 >> 2;
            int ic = icg * 8 + icl;
            wt2[i] = f2bf(c2w[(oc * 32 + ic) * 9 + tap]);
        } else if (i < 18432 + 1179648) {
            int j = i - 18432;
            wf1[j] = f2bf(f1w[j]);
        }
        return;
    }
    for (int e = tid; e < 288; e += 256) wl[e] = w1[e];
    if (tid < 32) bl[tid] = b1[tid];
    __syncthreads();
    int e = blk * 256 + tid;          // 2048*676*4 total, exact sub-grid
    int icg = e & 3;
    int t = e >> 2;
    int pix = t % 676;
    int b = t / 676;
    int y = pix / 26, xc = pix % 26;
    const float* xp = x + b * 784 + y * 28 + xc;
    float in9[9];
#pragma unroll
    for (int ky = 0; ky < 3; ++ky)
#pragma unroll
        for (int kx = 0; kx < 3; ++kx) in9[ky * 3 + kx] = xp[ky * 28 + kx];
    short8 outv;
#pragma unroll
    for (int o = 0; o < 8; ++o) {
        int oc = icg * 8 + o;
        float acc = bl[oc];
#pragma unroll
        for (int k = 0; k < 9; ++k) acc = fmaf(in9[k], wl[oc * 9 + k], acc);
        outv[o] = (short)f2bf(fmaxf(acc, 0.f));
    }
    *(short8*)&h1b[((b * 4 + icg) * 676 + pix) * 8] = outv;
}

// ---- conv2 persistent (r13/r15-proven): 256 blocks x 8 images, dbuf ----
#define EPILOG(ACC0, ACC1, RX, RY)                                                         \
    {                                                                                      \
        int pcolb = (RX) * 4 + 2 * hi;                                                     \
        _Pragma("unroll")                                                                  \
        for (int q = 0; q < 2; ++q) {                                                      \
            int prow = (RY) * 2 + q;                                                       \
            int bs = 8 * q;                                                                \
            float m00 = fmaxf(fmaxf(ACC0[bs], ACC0[bs + 1]), fmaxf(ACC0[bs + 4], ACC0[bs + 5])); \
            float m01 = fmaxf(fmaxf(ACC0[bs + 2], ACC0[bs + 3]), fmaxf(ACC0[bs + 6], ACC0[bs + 7])); \
            uint pk0 = (uint)f2bf(fmaxf(m00 + bias0, 0.f)) | ((uint)f2bf(fmaxf(m01 + bias0, 0.f)) << 16); \
            *(uint*)&pout[lo * 144 + prow * 12 + pcolb] = pk0;                             \
            float m10 = fmaxf(fmaxf(ACC1[bs], ACC1[bs + 1]), fmaxf(ACC1[bs + 4], ACC1[bs + 5])); \
            float m11 = fmaxf(fmaxf(ACC1[bs + 2], ACC1[bs + 3]), fmaxf(ACC1[bs + 6], ACC1[bs + 7])); \
            uint pk1 = (uint)f2bf(fmaxf(m10 + bias1, 0.f)) | ((uint)f2bf(fmaxf(m11 + bias1, 0.f)) << 16); \
            *(uint*)&pout[(lo + 32) * 144 + prow * 12 + pcolb] = pk1;                      \
        }                                                                                  \
    }

__global__ __launch_bounds__(384, 2) void conv2_persist(
    const ushort* __restrict__ h1b, const ushort* __restrict__ wt2,
    const float* __restrict__ c2b, ushort* __restrict__ pooled)
{
    __shared__ __attribute__((aligned(16))) ushort wt_lds[18432];     // [tap9][icg4][oc64][ic8]
    __shared__ __attribute__((aligned(16))) ushort in_lds[2][22016];  // [icg4][pix676][ic8] + pad
    int cu = blockIdx.x;              // 0..255, 8 images each
    int tid = threadIdx.x;
    int wave = tid >> 6;
    int lane = tid & 63;
    int lo = lane & 31;
    int hi = lane >> 5;

    for (int c = wave; c < 36; c += 6) {
        const ushort* src = wt2 + (size_t)(c * 64 + lane) * 8;
        __builtin_amdgcn_global_load_lds(GLB_CP(src), LDS_CP(wt_lds + c * 512), 16, 0, 0);
    }
    {
        const ushort* base = h1b + (size_t)(cu * 8) * 21632;
        for (int c = wave; c < 43; c += 6) {
            int e = c * 64 + lane;
            if (e > 2703) e = 2703;
            __builtin_amdgcn_global_load_lds(GLB_CP(base + (size_t)e * 8),
                                             LDS_CP(in_lds[0] + c * 512), 16, 0, 0);
        }
    }
    float bias0 = c2b[lo];
    float bias1 = c2b[lo + 32];
    __syncthreads();

    short8 A0r[9][2];
#pragma unroll
    for (int tap = 0; tap < 9; ++tap)
#pragma unroll
        for (int ks = 0; ks < 2; ++ks)
            A0r[tap][ks] = *(const short8*)&wt_lds[((tap * 4 + ks * 2 + hi) * 64 + lo) * 8];

    int pb[3];
#pragma unroll
    for (int i = 0; i < 3; ++i) {
        int r = wave + 6 * i;
        int rx = r % 3, ry = r / 3;
        int xcoord = rx * 8 + (lo & 7);
        int ycoord = ry * 4 + (lo >> 3);
        pb[i] = ycoord * 26 + xcoord;
    }
    int rx0 = wave % 3, ry0 = wave / 3;
    int rx1 = (wave + 6) % 3, ry1 = (wave + 6) / 3;
    int rx2 = (wave + 12) % 3, ry2 = (wave + 12) / 3;

    for (int j = 0; j < 8; ++j) {
        if (j < 7) {
            const ushort* base = h1b + (size_t)(cu * 8 + j + 1) * 21632;
            ushort* dst = in_lds[(j + 1) & 1];
            for (int c = wave; c < 43; c += 6) {
                int e = c * 64 + lane;
                if (e > 2703) e = 2703;
                __builtin_amdgcn_global_load_lds(GLB_CP(base + (size_t)e * 8),
                                                 LDS_CP(dst + c * 512), 16, 0, 0);
            }
        }

        const ushort* ib = in_lds[j & 1];
        f32x16 aA0 = (f32x16)0.f, aA1 = (f32x16)0.f;
        f32x16 aB0 = (f32x16)0.f, aB1 = (f32x16)0.f;
        f32x16 aC0 = (f32x16)0.f, aC1 = (f32x16)0.f;

#pragma unroll
        for (int tap = 0; tap < 9; ++tap) {
            int off = (tap / 3) * 26 + (tap % 3);
#pragma unroll
            for (int ks = 0; ks < 2; ++ks) {
                short8 a0 = A0r[tap][ks];
                short8 a1 = *(const short8*)&wt_lds[((tap * 4 + ks * 2 + hi) * 64 + 32 + lo) * 8];
                const ushort* ip = &ib[((ks * 2 + hi) * 676 + off) * 8];
                short8 b0 = *(const short8*)(ip + pb[0] * 8);
                short8 b1 = *(const short8*)(ip + pb[1] * 8);
                short8 b2 = *(const short8*)(ip + pb[2] * 8);
                aA0 = __builtin_amdgcn_mfma_f32_32x32x16_bf16(b0, a0, aA0, 0, 0, 0);
                aA1 = __builtin_amdgcn_mfma_f32_32x32x16_bf16(b0, a1, aA1, 0, 0, 0);
                aB0 = __builtin_amdgcn_mfma_f32_32x32x16_bf16(b1, a0, aB0, 0, 0, 0);
                aB1 = __builtin_amdgcn_mfma_f32_32x32x16_bf16(b1, a1, aB1, 0, 0, 0);
                aC0 = __builtin_amdgcn_mfma_f32_32x32x16_bf16(b2, a0, aC0, 0, 0, 0);
                aC1 = __builtin_amdgcn_mfma_f32_32x32x16_bf16(b2, a1, aC1, 0, 0, 0);
            }
        }

        ushort* pout = pooled + (size_t)(cu * 8 + j) * 9216;
        EPILOG(aA0, aA1, rx0, ry0)
        EPILOG(aB0, aB1, rx1, ry1)
        EPILOG(aC0, aC1, rx2, ry2)
        __syncthreads();
    }
}

// ---- fc1 MFMA: pooled[2048,9216]bf16 x wf1[128,9216]bf16^T, 4-way K-split ----
__global__ __launch_bounds__(256) void fc1_mfma(
    const ushort* __restrict__ pooled, const ushort* __restrict__ wf1,
    float* __restrict__ part)
{
    int bx = blockIdx.x, by = blockIdx.y;
    int tid = threadIdx.x;
    int wid = tid >> 6, lane = tid & 63;
    int lo = lane & 15, hi = lane >> 4;
    int m0 = bx * 32;
    int kb = by * 2304;

    f32x4 acc[2][2];
#pragma unroll
    for (int mt = 0; mt < 2; ++mt)
#pragma unroll
        for (int j = 0; j < 2; ++j) acc[mt][j] = (f32x4)0.f;

    const ushort* arow0 = pooled + (size_t)(m0 + lo) * 9216 + kb + hi * 8;
    const ushort* arow1 = arow0 + 16 * 9216;
    const ushort* brow0 = wf1 + (size_t)(wid * 32 + lo) * 9216 + kb + hi * 8;
    const ushort* brow1 = brow0 + 16 * 9216;

    for (int kt = 0; kt < 72; ++kt) {
        short8 a0 = *(const short8*)(arow0 + kt * 32);
        short8 a1 = *(const short8*)(arow1 + kt * 32);
        short8 b0 = *(const short8*)(brow0 + kt * 32);
        short8 b1 = *(const short8*)(brow1 + kt * 32);
        acc[0][0] = __builtin_amdgcn_mfma_f32_16x16x32_bf16(a0, b0, acc[0][0], 0, 0, 0);
        acc[1][0] = __builtin_amdgcn_mfma_f32_16x16x32_bf16(a1, b0, acc[1][0], 0, 0, 0);
        acc[0][1] = __builtin_amdgcn_mfma_f32_16x16x32_bf16(a0, b1, acc[0][1], 0, 0, 0);
        acc[1][1] = __builtin_amdgcn_mfma_f32_16x16x32_bf16(a1, b1, acc[1][1], 0, 0, 0);
    }
    float* pp = part + (size_t)by * 262144;
#pragma unroll
    for (int mt = 0; mt < 2; ++mt)
#pragma unroll
        for (int j = 0; j < 2; ++j)
#pragma unroll
            for (int r = 0; r < 4; ++r)
                pp[(m0 + mt * 16 + hi * 4 + r) * 128 + wid * 32 + j * 16 + lo] = acc[mt][j][r];
}

// ---------------- quantum (+fc1_reduce +fc2 fused prologue; r13-proven circuit) ------
__device__ __forceinline__ void apply_rot2(float2* s, int p, float2 m00, float2 m01,
                                           float2 m10, float2 m11, int tid)
{
    for (int q = tid; q < 512; q += 256) {
        int i0 = ((q >> p) << (p + 1)) | (q & ((1 << p) - 1));
        int i1 = i0 | (1 << p);
        float2 aa = s[i0], bb = s[i1];
        s[i0] = make_float2(m00.x * aa.x - m00.y * aa.y + m01.x * bb.x - m01.y * bb.y,
                            m00.x * aa.y + m00.y * aa.x + m01.x * bb.y + m01.y * bb.x);
        s[i1] = make_float2(m10.x * aa.x - m10.y * aa.y + m11.x * bb.x - m11.y * bb.y,
                            m10.x * aa.y + m10.y * aa.x + m11.x * bb.y + m11.y * bb.x);
    }
}

__global__ __launch_bounds__(256) void quantum_kernel(
    const float* __restrict__ part, const float* __restrict__ f1b,
    const float* __restrict__ f2w, const float* __restrict__ f2b,
    const float* __restrict__ theta0, const float* __restrict__ theta_rz,
    const float* __restrict__ theta_ps, const float* __restrict__ rot_p,
    float* __restrict__ out)
{
    __shared__ float2 s[1024];
    __shared__ float red[40];
    __shared__ float P[64];
    __shared__ float h[128];
    __shared__ float angs[16];
    int b = blockIdx.x;
    int tid = threadIdx.x;

    // fc1_reduce for row b (identical order: sum 4 parts, +bias, relu)
    if (tid < 128) {
        float v = part[0 * 262144 + b * 128 + tid] + part[1 * 262144 + b * 128 + tid]
                + part[2 * 262144 + b * 128 + tid] + part[3 * 262144 + b * 128 + tid];
        h[tid] = fmaxf(v + f1b[tid], 0.f);
    }
    __syncthreads();
    // fc2 (bit-identical serial 128-FMA per output) + sigmoid*2pi
    if (tid < 10) {
        const float* wp = f2w + tid * 128;
        float sacc = f2b[tid];
        for (int k = 0; k < 128; ++k) sacc = fmaf(h[k], wp[k], sacc);
        angs[tid] = 6.28318530718f / (1.f + expf(-sacc));
    }
    __syncthreads();

    if (tid < 13) {
        if (tid < 10) {
            int k = tid;
            float ak = angs[k];
            float th = theta0[k] + ak;
            if (k == 1) th += ak;
            if (k == 5) th -= 0.78539816339745f;
            float c, sn; sincosf(0.5f * th, &sn, &c);
            float2 v0 = make_float2(c, 0.f), v1 = make_float2(0.f, -sn);
            if (k == 0) v1 = make_float2(-sn, 0.f);
            if (k == 2) { float ca, sa; sincosf(0.5f * ak, &sa, &ca);
                float2 n0 = make_float2(ca * v0.x - sa * v1.x, ca * v0.y - sa * v1.y);
                float2 n1 = make_float2(sa * v0.x + ca * v1.x, sa * v0.y + ca * v1.y);
                v0 = n0; v1 = n1; }
            if (k == 3) { float ca, sa; sincosf(0.5f * ak, &sa, &ca);
                v0 = cmul(v0, make_float2(ca, -sa));
                v1 = cmul(v1, make_float2(ca, sa)); }
            if (k == 4) { float2 t = v1; v1 = make_float2(-t.y, t.x); }
            if (k == 5) { const float r = 0.70710678118655f;
                float2 t = v1; v1 = make_float2(r * (t.x - t.y), r * (t.x + t.y)); }
            if (k == 6) { float ca, sa; sincosf(0.5f * theta_rz[0], &sa, &ca);
                v0 = cmul(v0, make_float2(ca, -sa));
                v1 = cmul(v1, make_float2(ca, sa)); }
            if (k == 7) { float2 p = v0, q = v1;
                v0 = make_float2(0.5f * ((p.x - p.y) + (q.x + q.y)),
                                 0.5f * ((p.x + p.y) + (q.y - q.x)));
                v1 = make_float2(0.5f * ((p.x + p.y) + (q.x - q.y)),
                                 0.5f * ((p.y - p.x) + (q.x + q.y)));
                float c2, s2; sincosf(ak, &s2, &c2);
                v1 = cmul(v1, make_float2(c2, s2)); }
            P[k * 4 + 0] = v0.x; P[k * 4 + 1] = v0.y;
            P[k * 4 + 2] = v1.x; P[k * 4 + 3] = v1.y;
        } else if (tid == 10) {
            float c1, s1; sincosf(theta_ps[0], &s1, &c1);
            P[40] = c1; P[41] = s1;
        } else if (tid == 11) {
            float c, sn; sincosf(0.5f * rot_p[1], &sn, &c);
            float A = 0.5f * (rot_p[0] + rot_p[2]), Bv = 0.5f * (rot_p[0] - rot_p[2]);
            float cA, sA; sincosf(A, &sA, &cA);
            float cB, sB; sincosf(Bv, &sB, &cB);
            P[44] = cA * c;  P[45] = -sA * c;
            P[46] = -cB * sn; P[47] = -sB * sn;
            P[48] = cB * sn;  P[49] = -sB * sn;
            P[50] = cA * c;  P[51] = sA * c;
        } else {
            float a6 = angs[6], a7 = angs[7], a8 = angs[8];
            float c, sn; sincosf(0.5f * a7, &sn, &c);
            float A = 0.5f * (a6 + a8), Bv = 0.5f * (a6 - a8);
            float cA, sA; sincosf(A, &sA, &cA);
            float cB, sB; sincosf(Bv, &sB, &cB);
            P[52] = cA * c;  P[53] = -sA * c;
            P[54] = -cB * sn; P[55] = -sB * sn;
            P[56] = cB * sn;  P[57] = -sB * sn;
            P[58] = cA * c;  P[59] = sA * c;
        }
    }
    __syncthreads();

    float2 v[10][2];
#pragma unroll
    for (int k = 0; k < 10; ++k) {
        int slot = (k == 2) ? 3 : (k == 3) ? 2 : k;
        v[k][0] = make_float2(P[slot * 4], P[slot * 4 + 1]);
        v[k][1] = make_float2(P[slot * 4 + 2], P[slot * 4 + 3]);
    }

    for (int i = tid; i < 1024; i += 256) {
        float2 c = ((i >> 9) & 1) ? v[0][1] : v[0][0];
#pragma unroll
        for (int k = 1; k < 10; ++k) {
            float2 vk = ((i >> (9 - k)) & 1) ? v[k][1] : v[k][0];
            c = cmul(c, vk);
        }
        s[i] = c;
    }
    __syncthreads();

    { // CY(ctrl bit7, tgt bit1) + Phase(theta_ps) on bit1
        int j = tid;
        float2 p1 = make_float2(P[40], P[41]);
        int i0 = (j & 1) | (((j >> 1) & 31) << 2) | (((j >> 6) & 3) << 8) | 128;
        int i1 = i0 | 2;
        float2 t0 = s[i0], t1 = s[i1];
        s[i0] = make_float2(t1.y, -t1.x);
        s[i1] = cmul(make_float2(-t0.y, t0.x), p1);
        int i2 = (j & 1) | 2 | (((j >> 1) & 31) << 2) | (((j >> 6) & 3) << 8);
        s[i2] = cmul(s[i2], p1);
    }
    __syncthreads();
    if (tid < 128) {
        int j = tid;
        int i0 = (j & 7) | 16 | 32 | (((j >> 3) & 15) << 6);
        int i1 = i0 ^ 0x18;
        float2 t0 = s[i0], t1 = s[i1];
        s[i0] = t1; s[i1] = t0;
    }
    __syncthreads();
    if (tid < 128) {
        int j = tid;
        int i0 = (j & 1) | 2 | (((j >> 1) & 3) << 2) | 16 | (((j >> 3) & 15) << 5);
        int i1 = i0 | 512;
        float2 t0 = s[i0], t1 = s[i1];
        s[i0] = t1; s[i1] = t0;
    }
    __syncthreads();
    apply_rot2(s, 5, make_float2(P[44], P[45]), make_float2(P[46], P[47]),
               make_float2(P[48], P[49]), make_float2(P[50], P[51]), tid);
    __syncthreads();
    apply_rot2(s, 4, make_float2(P[52], P[53]), make_float2(P[54], P[55]),
               make_float2(P[56], P[57]), make_float2(P[58], P[59]), tid);
    __syncthreads();

    int wave = tid >> 6;
    for (int k = 0; k < 10; ++k) {
        int p = 9 - k;
        float part_ = 0.f;
        for (int q = tid; q < 512; q += 256) {
            int i0 = ((q >> p) << (p + 1)) | (q & ((1 << p) - 1));
            int i1 = i0 | (1 << p);
            float2 aa = s[i0], bb = s[i1];
            part_ += aa.x * bb.y - aa.y * bb.x;
        }
        part_ *= 2.f;
#pragma unroll
        for (int off = 32; off > 0; off >>= 1)
            part_ += __shfl_down(part_, off, 64);
        if ((tid & 63) == 0) red[k * 4 + wave] = part_;
    }
    __syncthreads();
    if (tid == 0) {
        float ev[10];
        float mx = -1e30f;
#pragma unroll
        for (int k = 0; k < 10; ++k) {
            ev[k] = red[k * 4] + red[k * 4 + 1] + red[k * 4 + 2] + red[k * 4 + 3];
            mx = fmaxf(mx, ev[k]);
        }
        float sum = 0.f;
#pragma unroll
        for (int k = 0; k < 10; ++k) sum += expf(ev[k] - mx);
        float lse = mx + logf(sum);
#pragma unroll
        for (int k = 0; k < 10; ++k) out[b * 10 + k] = ev[k] - lse;
    }
}

extern "C" void kernel_launch(void* const* d_in, const int* in_sizes, int n_in,
                              void* d_out, int out_size, void* d_ws, size_t ws_size,
                              hipStream_t stream)
{
    (void)in_sizes; (void)n_in; (void)out_size; (void)ws_size;
    const float* x    = (const float*)d_in[0];
    const float* c1w  = (const float*)d_in[1];
    const float* c1b  = (const float*)d_in[2];
    const float* c2w  = (const float*)d_in[3];
    const float* c2b  = (const float*)d_in[4];
    const float* f1w  = (const float*)d_in[5];
    const float* f1b  = (const float*)d_in[6];
    const float* f2w  = (const float*)d_in[7];
    const float* f2b  = (const float*)d_in[8];
    const float* th0  = (const float*)d_in[9];
    const float* trz  = (const float*)d_in[10];
    const float* tps  = (const float*)d_in[11];
    const float* rotp = (const float*)d_in[12];
    float* out = (float*)d_out;

    char* ws = (char*)d_ws;
    ushort* h1b    = (ushort*)(ws);                       // 88,604,672 B
    ushort* pooled = (ushort*)(ws + 88604672);            // 37,748,736 B
    ushort* wt2    = (ushort*)(ws + 126353408);           //     36,864 B
    ushort* wf1    = (ushort*)(ws + 126390272);           //  2,359,296 B
    float*  part   = (float*)(ws + 128749568);            //  4,194,304 B

    conv1_prep_kernel<<<26312, 256, 0, stream>>>(x, c1w, c1b, h1b, c2w, f1w, wt2, wf1);
    conv2_persist<<<256, 384, 0, stream>>>(h1b, wt2, c2b, pooled);
    fc1_mfma<<<dim3(64, 4), 256, 0, stream>>>(pooled, wf1, part);
    quantum_kernel<<<2048, 256, 0, stream>>>(part, f1b, f2w, f2b, th0, trz, tps, rotp, out);
}

// Round 17
// 134.984 us; speedup vs baseline: 1.2215x; 1.0412x over previous
//
#include <hip/hip_runtime.h>
#include <math.h>

typedef short short8 __attribute__((ext_vector_type(8)));
typedef float f32x4 __attribute__((ext_vector_type(4)));
typedef float f32x16 __attribute__((ext_vector_type(16)));

#define GLB_CP(p) ((const __attribute__((address_space(1))) void*)(p))
#define LDS_CP(p) ((__attribute__((address_space(3))) void*)(p))

__device__ __forceinline__ float2 cmul(float2 a, float2 b) {
    return make_float2(a.x * b.x - a.y * b.y, a.x * b.y + a.y * b.x);
}

__device__ __forceinline__ ushort f2bf(float f) {
    uint u = __float_as_uint(f);
    uint r = (u + 0x7FFFu + ((u >> 16) & 1u)) >> 16;
    return (ushort)r;
}

// ---- prep: conv2 weights -> wt2[tap][icg][oc][ic8] bf16 ; fc1 weights -> bf16 ----
__global__ __launch_bounds__(256) void prep_kernel(
    const float* __restrict__ c2w, const float* __restrict__ f1w,
    ushort* __restrict__ wt2, ushort* __restrict__ wf1)
{
    int i = blockIdx.x * 256 + threadIdx.x;
    if (i < 18432) {
        int icl = i & 7;
        int t = i >> 3;
        int oc = t & 63;
        int t2 = t >> 6;
        int icg = t2 & 3;
        int tap = t2 >> 2;
        int ic = icg * 8 + icl;
        wt2[i] = f2bf(c2w[(oc * 32 + ic) * 9 + tap]);
    } else if (i < 18432 + 1179648) {
        int j = i - 18432;
        wf1[j] = f2bf(f1w[j]);
    }
}

// ---- conv1 device helper: image in xs (784 f32, LDS) -> in_buf bf16 [icg][pix][ic8] ----
// bit-identical math to the old conv1 kernel (same fmaf order, same f2bf).
__device__ __forceinline__ void conv1_image(
    const float* xs, const float* w1s, const float* b1s,
    ushort* in_buf, int tstart, int tstride)
{
    for (int task = tstart; task < 2704; task += tstride) {
        int icg = task & 3;
        int pix = task >> 2;
        int y = pix / 26, xc = pix % 26;
        float in9[9];
#pragma unroll
        for (int ky = 0; ky < 3; ++ky)
#pragma unroll
            for (int kx = 0; kx < 3; ++kx)
                in9[ky * 3 + kx] = xs[(y + ky) * 28 + xc + kx];
        short8 ov;
#pragma unroll
        for (int o = 0; o < 8; ++o) {
            int oc = icg * 8 + o;
            float acc = b1s[oc];
#pragma unroll
            for (int k = 0; k < 9; ++k) acc = fmaf(in9[k], w1s[oc * 9 + k], acc);
            ov[o] = (short)f2bf(fmaxf(acc, 0.f));
        }
        *(short8*)&in_buf[(icg * 676 + pix) * 8] = ov;
    }
}

// ---- conv2 fused persistent: 256 blocks x 8 images, producer-consumer waves ----
// 512 thr = 8 waves: waves 0-5 MFMA consumers (18 regions, r13-proven math),
// waves 6-7 conv1 producers (image j+1 into alternate in_lds while consumers
// do image j). x prefetched 2 images ahead via tiny DMA. h1b round-trip deleted.
#define EPILOG(ACC0, ACC1, RX, RY)                                                         \
    {                                                                                      \
        int pcolb = (RX) * 4 + 2 * hi;                                                     \
        _Pragma("unroll")                                                                  \
        for (int q = 0; q < 2; ++q) {                                                      \
            int prow = (RY) * 2 + q;                                                       \
            int bs = 8 * q;                                                                \
            float m00 = fmaxf(fmaxf(ACC0[bs], ACC0[bs + 1]), fmaxf(ACC0[bs + 4], ACC0[bs + 5])); \
            float m01 = fmaxf(fmaxf(ACC0[bs + 2], ACC0[bs + 3]), fmaxf(ACC0[bs + 6], ACC0[bs + 7])); \
            uint pk0 = (uint)f2bf(fmaxf(m00 + bias0, 0.f)) | ((uint)f2bf(fmaxf(m01 + bias0, 0.f)) << 16); \
            *(uint*)&pout[lo * 144 + prow * 12 + pcolb] = pk0;                             \
            float m10 = fmaxf(fmaxf(ACC1[bs], ACC1[bs + 1]), fmaxf(ACC1[bs + 4], ACC1[bs + 5])); \
            float m11 = fmaxf(fmaxf(ACC1[bs + 2], ACC1[bs + 3]), fmaxf(ACC1[bs + 6], ACC1[bs + 7])); \
            uint pk1 = (uint)f2bf(fmaxf(m10 + bias1, 0.f)) | ((uint)f2bf(fmaxf(m11 + bias1, 0.f)) << 16); \
            *(uint*)&pout[(lo + 32) * 144 + prow * 12 + pcolb] = pk1;                      \
        }                                                                                  \
    }

__global__ __launch_bounds__(512, 1) void conv2_fused(
    const float* __restrict__ x, const float* __restrict__ c1w,
    const float* __restrict__ c1b, const ushort* __restrict__ wt2,
    const float* __restrict__ c2b, ushort* __restrict__ pooled)
{
    __shared__ __attribute__((aligned(16))) ushort wt_lds[18432];     // 36,864 B
    __shared__ __attribute__((aligned(16))) ushort in_lds[2][22016];  // 88,064 B
    __shared__ __attribute__((aligned(16))) float xs[2][1024];        //  8,192 B
    __shared__ float w1s[288];
    __shared__ float b1s[32];
    int cu = blockIdx.x;              // 0..255, 8 images each
    int tid = threadIdx.x;
    int wid = tid >> 6;
    int lane = tid & 63;
    int lo = lane & 31;
    int hi = lane >> 5;

    // prologue: weights DMA + conv1 params + x[0], x[1] DMA
    for (int c = wid; c < 36; c += 8) {
        const ushort* src = wt2 + (size_t)(c * 64 + lane) * 8;
        __builtin_amdgcn_global_load_lds(GLB_CP(src), LDS_CP(wt_lds + c * 512), 16, 0, 0);
    }
    for (int e = tid; e < 288; e += 512) w1s[e] = c1w[e];
    if (tid < 32) b1s[tid] = c1b[tid];
#pragma unroll
    for (int img = 0; img < 2; ++img) {
        const float* src = x + (size_t)(cu * 8 + img) * 784;
        for (int c = wid; c < 4; c += 8) {
            int e = c * 64 + lane;
            if (e > 195) e = 195;     // 784 floats = 196 x 16B units; clamp dups into pad
            __builtin_amdgcn_global_load_lds(GLB_CP(src + e * 4),
                                             LDS_CP(xs[img] + c * 256), 16, 0, 0);
        }
    }
    float bias0 = c2b[lo];
    float bias1 = c2b[lo + 32];
    __syncthreads();

    // conv1 image 0 by ALL threads
    conv1_image(xs[0], w1s, b1s, in_lds[0], tid, 512);
    __syncthreads();

    // consumer geometry (waves 0..5, 18 regions of 8x4)
    int pb[3];
#pragma unroll
    for (int i = 0; i < 3; ++i) {
        int r = wid + 6 * i;
        int rx = r % 3, ry = r / 3;
        pb[i] = (ry * 4 + (lo >> 3)) * 26 + rx * 8 + (lo & 7);
    }
    int rx0 = wid % 3, ry0 = wid / 3;
    int rx1 = (wid + 6) % 3, ry1 = (wid + 6) / 3;
    int rx2 = (wid + 12) % 3, ry2 = (wid + 12) / 3;

    for (int j = 0; j < 8; ++j) {
        if (wid < 6) {
            // MFMA phase on image j
            const ushort* ib = in_lds[j & 1];
            f32x16 aA0 = (f32x16)0.f, aA1 = (f32x16)0.f;
            f32x16 aB0 = (f32x16)0.f, aB1 = (f32x16)0.f;
            f32x16 aC0 = (f32x16)0.f, aC1 = (f32x16)0.f;
#pragma unroll
            for (int tap = 0; tap < 9; ++tap) {
                int off = (tap / 3) * 26 + (tap % 3);
#pragma unroll
                for (int ks = 0; ks < 2; ++ks) {
                    const ushort* wp = &wt_lds[((tap * 4 + ks * 2 + hi) * 64) * 8];
                    short8 a0 = *(const short8*)(wp + lo * 8);
                    short8 a1 = *(const short8*)(wp + (32 + lo) * 8);
                    const ushort* ip = &ib[((ks * 2 + hi) * 676 + off) * 8];
                    short8 b0 = *(const short8*)(ip + pb[0] * 8);
                    short8 b1 = *(const short8*)(ip + pb[1] * 8);
                    short8 b2 = *(const short8*)(ip + pb[2] * 8);
                    aA0 = __builtin_amdgcn_mfma_f32_32x32x16_bf16(b0, a0, aA0, 0, 0, 0);
                    aA1 = __builtin_amdgcn_mfma_f32_32x32x16_bf16(b0, a1, aA1, 0, 0, 0);
                    aB0 = __builtin_amdgcn_mfma_f32_32x32x16_bf16(b1, a0, aB0, 0, 0, 0);
                    aB1 = __builtin_amdgcn_mfma_f32_32x32x16_bf16(b1, a1, aB1, 0, 0, 0);
                    aC0 = __builtin_amdgcn_mfma_f32_32x32x16_bf16(b2, a0, aC0, 0, 0, 0);
                    aC1 = __builtin_amdgcn_mfma_f32_32x32x16_bf16(b2, a1, aC1, 0, 0, 0);
                }
            }
            ushort* pout = pooled + (size_t)(cu * 8 + j) * 9216;
            EPILOG(aA0, aA1, rx0, ry0)
            EPILOG(aB0, aB1, rx1, ry1)
            EPILOG(aC0, aC1, rx2, ry2)
        } else {
            // producers: DMA x[j+2] into xs[j&1] (x[j] dead), conv1 image j+1
            if (j + 2 <= 7) {
                const float* src = x + (size_t)(cu * 8 + j + 2) * 784;
                for (int c = (wid - 6) * 2; c < (wid - 6) * 2 + 2; ++c) {
                    int e = c * 64 + lane;
                    if (e > 195) e = 195;
                    __builtin_amdgcn_global_load_lds(GLB_CP(src + e * 4),
                                                     LDS_CP(xs[j & 1] + c * 256), 16, 0, 0);
                }
            }
            if (j + 1 <= 7)
                conv1_image(xs[(j + 1) & 1], w1s, b1s, in_lds[(j + 1) & 1], tid - 384, 128);
        }
        __syncthreads();   // drains DMA; publishes conv1 writes; frees buffers
    }
}

// ---- fc1 MFMA: pooled[2048,9216]bf16 x wf1[128,9216]bf16^T, 4-way K-split ----
__global__ __launch_bounds__(256) void fc1_mfma(
    const ushort* __restrict__ pooled, const ushort* __restrict__ wf1,
    float* __restrict__ part)
{
    int bx = blockIdx.x, by = blockIdx.y;
    int tid = threadIdx.x;
    int wid = tid >> 6, lane = tid & 63;
    int lo = lane & 15, hi = lane >> 4;
    int m0 = bx * 32;
    int kb = by * 2304;

    f32x4 acc[2][2];
#pragma unroll
    for (int mt = 0; mt < 2; ++mt)
#pragma unroll
        for (int j = 0; j < 2; ++j) acc[mt][j] = (f32x4)0.f;

    const ushort* arow0 = pooled + (size_t)(m0 + lo) * 9216 + kb + hi * 8;
    const ushort* arow1 = arow0 + 16 * 9216;
    const ushort* brow0 = wf1 + (size_t)(wid * 32 + lo) * 9216 + kb + hi * 8;
    const ushort* brow1 = brow0 + 16 * 9216;

    for (int kt = 0; kt < 72; ++kt) {
        short8 a0 = *(const short8*)(arow0 + kt * 32);
        short8 a1 = *(const short8*)(arow1 + kt * 32);
        short8 b0 = *(const short8*)(brow0 + kt * 32);
        short8 b1 = *(const short8*)(brow1 + kt * 32);
        acc[0][0] = __builtin_amdgcn_mfma_f32_16x16x32_bf16(a0, b0, acc[0][0], 0, 0, 0);
        acc[1][0] = __builtin_amdgcn_mfma_f32_16x16x32_bf16(a1, b0, acc[1][0], 0, 0, 0);
        acc[0][1] = __builtin_amdgcn_mfma_f32_16x16x32_bf16(a0, b1, acc[0][1], 0, 0, 0);
        acc[1][1] = __builtin_amdgcn_mfma_f32_16x16x32_bf16(a1, b1, acc[1][1], 0, 0, 0);
    }
    float* pp = part + (size_t)by * 262144;
#pragma unroll
    for (int mt = 0; mt < 2; ++mt)
#pragma unroll
        for (int j = 0; j < 2; ++j)
#pragma unroll
            for (int r = 0; r < 4; ++r)
                pp[(m0 + mt * 16 + hi * 4 + r) * 128 + wid * 32 + j * 16 + lo] = acc[mt][j][r];
}

// ---------------- quantum (+fc1_reduce +fc2 fused prologue; r13/r16-proven) ----------
__device__ __forceinline__ void apply_rot2(float2* s, int p, float2 m00, float2 m01,
                                           float2 m10, float2 m11, int tid)
{
    for (int q = tid; q < 512; q += 256) {
        int i0 = ((q >> p) << (p + 1)) | (q & ((1 << p) - 1));
        int i1 = i0 | (1 << p);
        float2 aa = s[i0], bb = s[i1];
        s[i0] = make_float2(m00.x * aa.x - m00.y * aa.y + m01.x * bb.x - m01.y * bb.y,
                            m00.x * aa.y + m00.y * aa.x + m01.x * bb.y + m01.y * bb.x);
        s[i1] = make_float2(m10.x * aa.x - m10.y * aa.y + m11.x * bb.x - m11.y * bb.y,
                            m10.x * aa.y + m10.y * aa.x + m11.x * bb.y + m11.y * bb.x);
    }
}

__global__ __launch_bounds__(256) void quantum_kernel(
    const float* __restrict__ part, const float* __restrict__ f1b,
    const float* __restrict__ f2w, const float* __restrict__ f2b,
    const float* __restrict__ theta0, const float* __restrict__ theta_rz,
    const float* __restrict__ theta_ps, const float* __restrict__ rot_p,
    float* __restrict__ out)
{
    __shared__ float2 s[1024];
    __shared__ float red[40];
    __shared__ float P[64];
    __shared__ float h[128];
    __shared__ float angs[16];
    int b = blockIdx.x;
    int tid = threadIdx.x;

    if (tid < 128) {
        float v = part[0 * 262144 + b * 128 + tid] + part[1 * 262144 + b * 128 + tid]
                + part[2 * 262144 + b * 128 + tid] + part[3 * 262144 + b * 128 + tid];
        h[tid] = fmaxf(v + f1b[tid], 0.f);
    }
    __syncthreads();
    if (tid < 10) {
        const float* wp = f2w + tid * 128;
        float sacc = f2b[tid];
        for (int k = 0; k < 128; ++k) sacc = fmaf(h[k], wp[k], sacc);
        angs[tid] = 6.28318530718f / (1.f + expf(-sacc));
    }
    __syncthreads();

    if (tid < 13) {
        if (tid < 10) {
            int k = tid;
            float ak = angs[k];
            float th = theta0[k] + ak;
            if (k == 1) th += ak;
            if (k == 5) th -= 0.78539816339745f;
            float c, sn; sincosf(0.5f * th, &sn, &c);
            float2 v0 = make_float2(c, 0.f), v1 = make_float2(0.f, -sn);
            if (k == 0) v1 = make_float2(-sn, 0.f);
            if (k == 2) { float ca, sa; sincosf(0.5f * ak, &sa, &ca);
                float2 n0 = make_float2(ca * v0.x - sa * v1.x, ca * v0.y - sa * v1.y);
                float2 n1 = make_float2(sa * v0.x + ca * v1.x, sa * v0.y + ca * v1.y);
                v0 = n0; v1 = n1; }
            if (k == 3) { float ca, sa; sincosf(0.5f * ak, &sa, &ca);
                v0 = cmul(v0, make_float2(ca, -sa));
                v1 = cmul(v1, make_float2(ca, sa)); }
            if (k == 4) { float2 t = v1; v1 = make_float2(-t.y, t.x); }
            if (k == 5) { const float r = 0.70710678118655f;
                float2 t = v1; v1 = make_float2(r * (t.x - t.y), r * (t.x + t.y)); }
            if (k == 6) { float ca, sa; sincosf(0.5f * theta_rz[0], &sa, &ca);
                v0 = cmul(v0, make_float2(ca, -sa));
                v1 = cmul(v1, make_float2(ca, sa)); }
            if (k == 7) { float2 p = v0, q = v1;
                v0 = make_float2(0.5f * ((p.x - p.y) + (q.x + q.y)),
                                 0.5f * ((p.x + p.y) + (q.y - q.x)));
                v1 = make_float2(0.5f * ((p.x + p.y) + (q.x - q.y)),
                                 0.5f * ((p.y - p.x) + (q.x + q.y)));
                float c2, s2; sincosf(ak, &s2, &c2);
                v1 = cmul(v1, make_float2(c2, s2)); }
            P[k * 4 + 0] = v0.x; P[k * 4 + 1] = v0.y;
            P[k * 4 + 2] = v1.x; P[k * 4 + 3] = v1.y;
        } else if (tid == 10) {
            float c1, s1; sincosf(theta_ps[0], &s1, &c1);
            P[40] = c1; P[41] = s1;
        } else if (tid == 11) {
            float c, sn; sincosf(0.5f * rot_p[1], &sn, &c);
            float A = 0.5f * (rot_p[0] + rot_p[2]), Bv = 0.5f * (rot_p[0] - rot_p[2]);
            float cA, sA; sincosf(A, &sA, &cA);
            float cB, sB; sincosf(Bv, &sB, &cB);
            P[44] = cA * c;  P[45] = -sA * c;
            P[46] = -cB * sn; P[47] = -sB * sn;
            P[48] = cB * sn;  P[49] = -sB * sn;
            P[50] = cA * c;  P[51] = sA * c;
        } else {
            float a6 = angs[6], a7 = angs[7], a8 = angs[8];
            float c, sn; sincosf(0.5f * a7, &sn, &c);
            float A = 0.5f * (a6 + a8), Bv = 0.5f * (a6 - a8);
            float cA, sA; sincosf(A, &sA, &cA);
            float cB, sB; sincosf(Bv, &sB, &cB);
            P[52] = cA * c;  P[53] = -sA * c;
            P[54] = -cB * sn; P[55] = -sB * sn;
            P[56] = cB * sn;  P[57] = -sB * sn;
            P[58] = cA * c;  P[59] = sA * c;
        }
    }
    __syncthreads();

    float2 v[10][2];
#pragma unroll
    for (int k = 0; k < 10; ++k) {
        int slot = (k == 2) ? 3 : (k == 3) ? 2 : k;
        v[k][0] = make_float2(P[slot * 4], P[slot * 4 + 1]);
        v[k][1] = make_float2(P[slot * 4 + 2], P[slot * 4 + 3]);
    }

    for (int i = tid; i < 1024; i += 256) {
        float2 c = ((i >> 9) & 1) ? v[0][1] : v[0][0];
#pragma unroll
        for (int k = 1; k < 10; ++k) {
            float2 vk = ((i >> (9 - k)) & 1) ? v[k][1] : v[k][0];
            c = cmul(c, vk);
        }
        s[i] = c;
    }
    __syncthreads();

    { // CY(ctrl bit7, tgt bit1) + Phase(theta_ps) on bit1
        int j = tid;
        float2 p1 = make_float2(P[40], P[41]);
        int i0 = (j & 1) | (((j >> 1) & 31) << 2) | (((j >> 6) & 3) << 8) | 128;
        int i1 = i0 | 2;
        float2 t0 = s[i0], t1 = s[i1];
        s[i0] = make_float2(t1.y, -t1.x);
        s[i1] = cmul(make_float2(-t0.y, t0.x), p1);
        int i2 = (j & 1) | 2 | (((j >> 1) & 31) << 2) | (((j >> 6) & 3) << 8);
        s[i2] = cmul(s[i2], p1);
    }
    __syncthreads();
    if (tid < 128) {
        int j = tid;
        int i0 = (j & 7) | 16 | 32 | (((j >> 3) & 15) << 6);
        int i1 = i0 ^ 0x18;
        float2 t0 = s[i0], t1 = s[i1];
        s[i0] = t1; s[i1] = t0;
    }
    __syncthreads();
    if (tid < 128) {
        int j = tid;
        int i0 = (j & 1) | 2 | (((j >> 1) & 3) << 2) | 16 | (((j >> 3) & 15) << 5);
        int i1 = i0 | 512;
        float2 t0 = s[i0], t1 = s[i1];
        s[i0] = t1; s[i1] = t0;
    }
    __syncthreads();
    apply_rot2(s, 5, make_float2(P[44], P[45]), make_float2(P[46], P[47]),
               make_float2(P[48], P[49]), make_float2(P[50], P[51]), tid);
    __syncthreads();
    apply_rot2(s, 4, make_float2(P[52], P[53]), make_float2(P[54], P[55]),
               make_float2(P[56], P[57]), make_float2(P[58], P[59]), tid);
    __syncthreads();

    int wave = tid >> 6;
    for (int k = 0; k < 10; ++k) {
        int p = 9 - k;
        float part_ = 0.f;
        for (int q = tid; q < 512; q += 256) {
            int i0 = ((q >> p) << (p + 1)) | (q & ((1 << p) - 1));
            int i1 = i0 | (1 << p);
            float2 aa = s[i0], bb = s[i1];
            part_ += aa.x * bb.y - aa.y * bb.x;
        }
        part_ *= 2.f;
#pragma unroll
        for (int off = 32; off > 0; off >>= 1)
            part_ += __shfl_down(part_, off, 64);
        if ((tid & 63) == 0) red[k * 4 + wave] = part_;
    }
    __syncthreads();
    if (tid == 0) {
        float ev[10];
        float mx = -1e30f;
#pragma unroll
        for (int k = 0; k < 10; ++k) {
            ev[k] = red[k * 4] + red[k * 4 + 1] + red[k * 4 + 2] + red[k * 4 + 3];
            mx = fmaxf(mx, ev[k]);
        }
        float sum = 0.f;
#pragma unroll
        for (int k = 0; k < 10; ++k) sum += expf(ev[k] - mx);
        float lse = mx + logf(sum);
#pragma unroll
        for (int k = 0; k < 10; ++k) out[b * 10 + k] = ev[k] - lse;
    }
}

extern "C" void kernel_launch(void* const* d_in, const int* in_sizes, int n_in,
                              void* d_out, int out_size, void* d_ws, size_t ws_size,
                              hipStream_t stream)
{
    (void)in_sizes; (void)n_in; (void)out_size; (void)ws_size;
    const float* x    = (const float*)d_in[0];
    const float* c1w  = (const float*)d_in[1];
    const float* c1b  = (const float*)d_in[2];
    const float* c2w  = (const float*)d_in[3];
    const float* c2b  = (const float*)d_in[4];
    const float* f1w  = (const float*)d_in[5];
    const float* f1b  = (const float*)d_in[6];
    const float* f2w  = (const float*)d_in[7];
    const float* f2b  = (const float*)d_in[8];
    const float* th0  = (const float*)d_in[9];
    const float* trz  = (const float*)d_in[10];
    const float* tps  = (const float*)d_in[11];
    const float* rotp = (const float*)d_in[12];
    float* out = (float*)d_out;

    char* ws = (char*)d_ws;
    ushort* pooled = (ushort*)(ws);                       // 37,748,736 B
    ushort* wt2    = (ushort*)(ws + 37748736);            //     36,864 B
    ushort* wf1    = (ushort*)(ws + 37785600);            //  2,359,296 B
    float*  part   = (float*)(ws + 40144896);             //  4,194,304 B

    prep_kernel<<<4680, 256, 0, stream>>>(c2w, f1w, wt2, wf1);
    conv2_fused<<<256, 512, 0, stream>>>(x, c1w, c1b, wt2, c2b, pooled);
    fc1_mfma<<<dim3(64, 4), 256, 0, stream>>>(pooled, wf1, part);
    quantum_kernel<<<2048, 256, 0, stream>>>(part, f1b, f2w, f2b, th0, trz, tps, rotp, out);
}

// Round 18
// 134.624 us; speedup vs baseline: 1.2247x; 1.0027x over previous
//
#include <hip/hip_runtime.h>
#include <math.h>

typedef short short8 __attribute__((ext_vector_type(8)));
typedef float f32x4 __attribute__((ext_vector_type(4)));
typedef float f32x16 __attribute__((ext_vector_type(16)));

#define GLB_CP(p) ((const __attribute__((address_space(1))) void*)(p))
#define LDS_CP(p) ((__attribute__((address_space(3))) void*)(p))

__device__ __forceinline__ float2 cmul(float2 a, float2 b) {
    return make_float2(a.x * b.x - a.y * b.y, a.x * b.y + a.y * b.x);
}

__device__ __forceinline__ ushort f2bf(float f) {
    uint u = __float_as_uint(f);
    uint r = (u + 0x7FFFu + ((u >> 16) & 1u)) >> 16;
    return (ushort)r;
}

// ---- prep: conv2 weights -> wt2[tap][icg][oc][ic8] bf16 ; fc1 weights -> bf16 ----
__global__ __launch_bounds__(256) void prep_kernel(
    const float* __restrict__ c2w, const float* __restrict__ f1w,
    ushort* __restrict__ wt2, ushort* __restrict__ wf1)
{
    int i = blockIdx.x * 256 + threadIdx.x;
    if (i < 18432) {
        int icl = i & 7;
        int t = i >> 3;
        int oc = t & 63;
        int t2 = t >> 6;
        int icg = t2 & 3;
        int tap = t2 >> 2;
        int ic = icg * 8 + icl;
        wt2[i] = f2bf(c2w[(oc * 32 + ic) * 9 + tap]);
    } else if (i < 18432 + 1179648) {
        int j = i - 18432;
        wf1[j] = f2bf(f1w[j]);
    }
}

// ---- conv1 helper (LDS weights; used once in prologue by all threads) ----
__device__ __forceinline__ void conv1_image(
    const float* xs, const float* w1s, const float* b1s,
    ushort* in_buf, int tstart, int tstride)
{
    for (int task = tstart; task < 2704; task += tstride) {
        int icg = task & 3;
        int pix = task >> 2;
        int y = pix / 26, xc = pix % 26;
        float in9[9];
#pragma unroll
        for (int ky = 0; ky < 3; ++ky)
#pragma unroll
            for (int kx = 0; kx < 3; ++kx)
                in9[ky * 3 + kx] = xs[(y + ky) * 28 + xc + kx];
        short8 ov;
#pragma unroll
        for (int o = 0; o < 8; ++o) {
            int oc = icg * 8 + o;
            float acc = b1s[oc];
#pragma unroll
            for (int k = 0; k < 9; ++k) acc = fmaf(in9[k], w1s[oc * 9 + k], acc);
            ov[o] = (short)f2bf(fmaxf(acc, 0.f));
        }
        *(short8*)&in_buf[(icg * 676 + pix) * 8] = ov;
    }
}

// ---- conv2 fused persistent: producer conv1 now register-weight-resident ----
#define EPILOG(ACC0, ACC1, RX, RY)                                                         \
    {                                                                                      \
        int pcolb = (RX) * 4 + 2 * hi;                                                     \
        _Pragma("unroll")                                                                  \
        for (int q = 0; q < 2; ++q) {                                                      \
            int prow = (RY) * 2 + q;                                                       \
            int bs = 8 * q;                                                                \
            float m00 = fmaxf(fmaxf(ACC0[bs], ACC0[bs + 1]), fmaxf(ACC0[bs + 4], ACC0[bs + 5])); \
            float m01 = fmaxf(fmaxf(ACC0[bs + 2], ACC0[bs + 3]), fmaxf(ACC0[bs + 6], ACC0[bs + 7])); \
            uint pk0 = (uint)f2bf(fmaxf(m00 + bias0, 0.f)) | ((uint)f2bf(fmaxf(m01 + bias0, 0.f)) << 16); \
            *(uint*)&pout[lo * 144 + prow * 12 + pcolb] = pk0;                             \
            float m10 = fmaxf(fmaxf(ACC1[bs], ACC1[bs + 1]), fmaxf(ACC1[bs + 4], ACC1[bs + 5])); \
            float m11 = fmaxf(fmaxf(ACC1[bs + 2], ACC1[bs + 3]), fmaxf(ACC1[bs + 6], ACC1[bs + 7])); \
            uint pk1 = (uint)f2bf(fmaxf(m10 + bias1, 0.f)) | ((uint)f2bf(fmaxf(m11 + bias1, 0.f)) << 16); \
            *(uint*)&pout[(lo + 32) * 144 + prow * 12 + pcolb] = pk1;                      \
        }                                                                                  \
    }

__global__ __launch_bounds__(512, 1) void conv2_fused(
    const float* __restrict__ x, const float* __restrict__ c1w,
    const float* __restrict__ c1b, const ushort* __restrict__ wt2,
    const float* __restrict__ c2b, ushort* __restrict__ pooled)
{
    __shared__ __attribute__((aligned(16))) ushort wt_lds[18432];     // 36,864 B
    __shared__ __attribute__((aligned(16))) ushort in_lds[2][22016];  // 88,064 B
    __shared__ __attribute__((aligned(16))) float xs[2][1024];        //  8,192 B
    __shared__ float w1s[288];
    __shared__ float b1s[32];
    int cu = blockIdx.x;              // 0..255, 8 images each
    int tid = threadIdx.x;
    int wid = tid >> 6;
    int lane = tid & 63;
    int lo = lane & 31;
    int hi = lane >> 5;

    // prologue: weights DMA + conv1 params + x[0], x[1] DMA
    for (int c = wid; c < 36; c += 8) {
        const ushort* src = wt2 + (size_t)(c * 64 + lane) * 8;
        __builtin_amdgcn_global_load_lds(GLB_CP(src), LDS_CP(wt_lds + c * 512), 16, 0, 0);
    }
    for (int e = tid; e < 288; e += 512) w1s[e] = c1w[e];
    if (tid < 32) b1s[tid] = c1b[tid];
#pragma unroll
    for (int img = 0; img < 2; ++img) {
        const float* src = x + (size_t)(cu * 8 + img) * 784;
        for (int c = wid; c < 4; c += 8) {
            int e = c * 64 + lane;
            if (e > 195) e = 195;     // clamp dups into pad
            __builtin_amdgcn_global_load_lds(GLB_CP(src + e * 4),
                                             LDS_CP(xs[img] + c * 256), 16, 0, 0);
        }
    }
    float bias0 = c2b[lo];
    float bias1 = c2b[lo + 32];
    __syncthreads();

    // conv1 image 0 by ALL threads (LDS-weight path, once)
    conv1_image(xs[0], w1s, b1s, in_lds[0], tid, 512);

    // producers hoist their icg's conv1 weights into VGPRs (compile-time indexed)
    float w1r[72];
    float b1r[8];
    int picg = tid & 3;               // == (tid-384)&3 for producers
    int pix0 = (tid & 63) >> 2 | ((tid >> 6) & 1) << 4;  // unused by consumers
    pix0 = (tid - 384) >> 2;          // 0..31 for producers (garbage for consumers, unused)
    if (wid >= 6) {
#pragma unroll
        for (int o = 0; o < 8; ++o) {
            b1r[o] = b1s[picg * 8 + o];
#pragma unroll
            for (int k = 0; k < 9; ++k)
                w1r[o * 9 + k] = w1s[(picg * 8 + o) * 9 + k];
        }
    }
    __syncthreads();

    // consumer geometry (waves 0..5, 18 regions of 8x4)
    int pb[3];
#pragma unroll
    for (int i = 0; i < 3; ++i) {
        int r = wid + 6 * i;
        int rx = r % 3, ry = r / 3;
        pb[i] = (ry * 4 + (lo >> 3)) * 26 + rx * 8 + (lo & 7);
    }
    int rx0 = wid % 3, ry0 = wid / 3;
    int rx1 = (wid + 6) % 3, ry1 = (wid + 6) / 3;
    int rx2 = (wid + 12) % 3, ry2 = (wid + 12) / 3;

    for (int j = 0; j < 8; ++j) {
        if (wid < 6) {
            const ushort* ib = in_lds[j & 1];
            f32x16 aA0 = (f32x16)0.f, aA1 = (f32x16)0.f;
            f32x16 aB0 = (f32x16)0.f, aB1 = (f32x16)0.f;
            f32x16 aC0 = (f32x16)0.f, aC1 = (f32x16)0.f;
#pragma unroll
            for (int tap = 0; tap < 9; ++tap) {
                int off = (tap / 3) * 26 + (tap % 3);
#pragma unroll
                for (int ks = 0; ks < 2; ++ks) {
                    const ushort* wp = &wt_lds[((tap * 4 + ks * 2 + hi) * 64) * 8];
                    short8 a0 = *(const short8*)(wp + lo * 8);
                    short8 a1 = *(const short8*)(wp + (32 + lo) * 8);
                    const ushort* ip = &ib[((ks * 2 + hi) * 676 + off) * 8];
                    short8 b0 = *(const short8*)(ip + pb[0] * 8);
                    short8 b1 = *(const short8*)(ip + pb[1] * 8);
                    short8 b2 = *(const short8*)(ip + pb[2] * 8);
                    aA0 = __builtin_amdgcn_mfma_f32_32x32x16_bf16(b0, a0, aA0, 0, 0, 0);
                    aA1 = __builtin_amdgcn_mfma_f32_32x32x16_bf16(b0, a1, aA1, 0, 0, 0);
                    aB0 = __builtin_amdgcn_mfma_f32_32x32x16_bf16(b1, a0, aB0, 0, 0, 0);
                    aB1 = __builtin_amdgcn_mfma_f32_32x32x16_bf16(b1, a1, aB1, 0, 0, 0);
                    aC0 = __builtin_amdgcn_mfma_f32_32x32x16_bf16(b2, a0, aC0, 0, 0, 0);
                    aC1 = __builtin_amdgcn_mfma_f32_32x32x16_bf16(b2, a1, aC1, 0, 0, 0);
                }
            }
            ushort* pout = pooled + (size_t)(cu * 8 + j) * 9216;
            EPILOG(aA0, aA1, rx0, ry0)
            EPILOG(aB0, aB1, rx1, ry1)
            EPILOG(aC0, aC1, rx2, ry2)
        } else {
            // producers: DMA x[j+2]; conv1 image j+1 with REGISTER weights
            if (j + 2 <= 7) {
                const float* src = x + (size_t)(cu * 8 + j + 2) * 784;
                for (int c = (wid - 6) * 2; c < (wid - 6) * 2 + 2; ++c) {
                    int e = c * 64 + lane;
                    if (e > 195) e = 195;
                    __builtin_amdgcn_global_load_lds(GLB_CP(src + e * 4),
                                                     LDS_CP(xs[j & 1] + c * 256), 16, 0, 0);
                }
            }
            if (j + 1 <= 7) {
                const float* xsrc = xs[(j + 1) & 1];
                ushort* in_buf = in_lds[(j + 1) & 1];
                for (int pix = pix0; pix < 676; pix += 32) {
                    int y = pix / 26, xc = pix % 26;
                    float in9[9];
#pragma unroll
                    for (int ky = 0; ky < 3; ++ky)
#pragma unroll
                        for (int kx = 0; kx < 3; ++kx)
                            in9[ky * 3 + kx] = xsrc[(y + ky) * 28 + xc + kx];
                    short8 ov;
#pragma unroll
                    for (int o = 0; o < 8; ++o) {
                        float acc = b1r[o];
#pragma unroll
                        for (int k = 0; k < 9; ++k)
                            acc = fmaf(in9[k], w1r[o * 9 + k], acc);
                        ov[o] = (short)f2bf(fmaxf(acc, 0.f));
                    }
                    *(short8*)&in_buf[(picg * 676 + pix) * 8] = ov;
                }
            }
        }
        __syncthreads();   // drains DMA; publishes conv1 writes; frees buffers
    }
}

// ---- fc1 MFMA: pooled[2048,9216]bf16 x wf1[128,9216]bf16^T, 4-way K-split ----
__global__ __launch_bounds__(256) void fc1_mfma(
    const ushort* __restrict__ pooled, const ushort* __restrict__ wf1,
    float* __restrict__ part)
{
    int bx = blockIdx.x, by = blockIdx.y;
    int tid = threadIdx.x;
    int wid = tid >> 6, lane = tid & 63;
    int lo = lane & 15, hi = lane >> 4;
    int m0 = bx * 32;
    int kb = by * 2304;

    f32x4 acc[2][2];
#pragma unroll
    for (int mt = 0; mt < 2; ++mt)
#pragma unroll
        for (int j = 0; j < 2; ++j) acc[mt][j] = (f32x4)0.f;

    const ushort* arow0 = pooled + (size_t)(m0 + lo) * 9216 + kb + hi * 8;
    const ushort* arow1 = arow0 + 16 * 9216;
    const ushort* brow0 = wf1 + (size_t)(wid * 32 + lo) * 9216 + kb + hi * 8;
    const ushort* brow1 = brow0 + 16 * 9216;

    for (int kt = 0; kt < 72; ++kt) {
        short8 a0 = *(const short8*)(arow0 + kt * 32);
        short8 a1 = *(const short8*)(arow1 + kt * 32);
        short8 b0 = *(const short8*)(brow0 + kt * 32);
        short8 b1 = *(const short8*)(brow1 + kt * 32);
        acc[0][0] = __builtin_amdgcn_mfma_f32_16x16x32_bf16(a0, b0, acc[0][0], 0, 0, 0);
        acc[1][0] = __builtin_amdgcn_mfma_f32_16x16x32_bf16(a1, b0, acc[1][0], 0, 0, 0);
        acc[0][1] = __builtin_amdgcn_mfma_f32_16x16x32_bf16(a0, b1, acc[0][1], 0, 0, 0);
        acc[1][1] = __builtin_amdgcn_mfma_f32_16x16x32_bf16(a1, b1, acc[1][1], 0, 0, 0);
    }
    float* pp = part + (size_t)by * 262144;
#pragma unroll
    for (int mt = 0; mt < 2; ++mt)
#pragma unroll
        for (int j = 0; j < 2; ++j)
#pragma unroll
            for (int r = 0; r < 4; ++r)
                pp[(m0 + mt * 16 + hi * 4 + r) * 128 + wid * 32 + j * 16 + lo] = acc[mt][j][r];
}

// ---------------- quantum (+fc1_reduce +fc2 fused prologue; r13/r16-proven) ----------
__device__ __forceinline__ void apply_rot2(float2* s, int p, float2 m00, float2 m01,
                                           float2 m10, float2 m11, int tid)
{
    for (int q = tid; q < 512; q += 256) {
        int i0 = ((q >> p) << (p + 1)) | (q & ((1 << p) - 1));
        int i1 = i0 | (1 << p);
        float2 aa = s[i0], bb = s[i1];
        s[i0] = make_float2(m00.x * aa.x - m00.y * aa.y + m01.x * bb.x - m01.y * bb.y,
                            m00.x * aa.y + m00.y * aa.x + m01.x * bb.y + m01.y * bb.x);
        s[i1] = make_float2(m10.x * aa.x - m10.y * aa.y + m11.x * bb.x - m11.y * bb.y,
                            m10.x * aa.y + m10.y * aa.x + m11.x * bb.y + m11.y * bb.x);
    }
}

__global__ __launch_bounds__(256) void quantum_kernel(
    const float* __restrict__ part, const float* __restrict__ f1b,
    const float* __restrict__ f2w, const float* __restrict__ f2b,
    const float* __restrict__ theta0, const float* __restrict__ theta_rz,
    const float* __restrict__ theta_ps, const float* __restrict__ rot_p,
    float* __restrict__ out)
{
    __shared__ float2 s[1024];
    __shared__ float red[40];
    __shared__ float P[64];
    __shared__ float h[128];
    __shared__ float angs[16];
    int b = blockIdx.x;
    int tid = threadIdx.x;

    if (tid < 128) {
        float v = part[0 * 262144 + b * 128 + tid] + part[1 * 262144 + b * 128 + tid]
                + part[2 * 262144 + b * 128 + tid] + part[3 * 262144 + b * 128 + tid];
        h[tid] = fmaxf(v + f1b[tid], 0.f);
    }
    __syncthreads();
    if (tid < 10) {
        const float* wp = f2w + tid * 128;
        float sacc = f2b[tid];
        for (int k = 0; k < 128; ++k) sacc = fmaf(h[k], wp[k], sacc);
        angs[tid] = 6.28318530718f / (1.f + expf(-sacc));
    }
    __syncthreads();

    if (tid < 13) {
        if (tid < 10) {
            int k = tid;
            float ak = angs[k];
            float th = theta0[k] + ak;
            if (k == 1) th += ak;
            if (k == 5) th -= 0.78539816339745f;
            float c, sn; sincosf(0.5f * th, &sn, &c);
            float2 v0 = make_float2(c, 0.f), v1 = make_float2(0.f, -sn);
            if (k == 0) v1 = make_float2(-sn, 0.f);
            if (k == 2) { float ca, sa; sincosf(0.5f * ak, &sa, &ca);
                float2 n0 = make_float2(ca * v0.x - sa * v1.x, ca * v0.y - sa * v1.y);
                float2 n1 = make_float2(sa * v0.x + ca * v1.x, sa * v0.y + ca * v1.y);
                v0 = n0; v1 = n1; }
            if (k == 3) { float ca, sa; sincosf(0.5f * ak, &sa, &ca);
                v0 = cmul(v0, make_float2(ca, -sa));
                v1 = cmul(v1, make_float2(ca, sa)); }
            if (k == 4) { float2 t = v1; v1 = make_float2(-t.y, t.x); }
            if (k == 5) { const float r = 0.70710678118655f;
                float2 t = v1; v1 = make_float2(r * (t.x - t.y), r * (t.x + t.y)); }
            if (k == 6) { float ca, sa; sincosf(0.5f * theta_rz[0], &sa, &ca);
                v0 = cmul(v0, make_float2(ca, -sa));
                v1 = cmul(v1, make_float2(ca, sa)); }
            if (k == 7) { float2 p = v0, q = v1;
                v0 = make_float2(0.5f * ((p.x - p.y) + (q.x + q.y)),
                                 0.5f * ((p.x + p.y) + (q.y - q.x)));
                v1 = make_float2(0.5f * ((p.x + p.y) + (q.x - q.y)),
                                 0.5f * ((p.y - p.x) + (q.x + q.y)));
                float c2, s2; sincosf(ak, &s2, &c2);
                v1 = cmul(v1, make_float2(c2, s2)); }
            P[k * 4 + 0] = v0.x; P[k * 4 + 1] = v0.y;
            P[k * 4 + 2] = v1.x; P[k * 4 + 3] = v1.y;
        } else if (tid == 10) {
            float c1, s1; sincosf(theta_ps[0], &s1, &c1);
            P[40] = c1; P[41] = s1;
        } else if (tid == 11) {
            float c, sn; sincosf(0.5f * rot_p[1], &sn, &c);
            float A = 0.5f * (rot_p[0] + rot_p[2]), Bv = 0.5f * (rot_p[0] - rot_p[2]);
            float cA, sA; sincosf(A, &sA, &cA);
            float cB, sB; sincosf(Bv, &sB, &cB);
            P[44] = cA * c;  P[45] = -sA * c;
            P[46] = -cB * sn; P[47] = -sB * sn;
            P[48] = cB * sn;  P[49] = -sB * sn;
            P[50] = cA * c;  P[51] = sA * c;
        } else {
            float a6 = angs[6], a7 = angs[7], a8 = angs[8];
            float c, sn; sincosf(0.5f * a7, &sn, &c);
            float A = 0.5f * (a6 + a8), Bv = 0.5f * (a6 - a8);
            float cA, sA; sincosf(A, &sA, &cA);
            float cB, sB; sincosf(Bv, &sB, &cB);
            P[52] = cA * c;  P[53] = -sA * c;
            P[54] = -cB * sn; P[55] = -sB * sn;
            P[56] = cB * sn;  P[57] = -sB * sn;
            P[58] = cA * c;  P[59] = sA * c;
        }
    }
    __syncthreads();

    float2 v[10][2];
#pragma unroll
    for (int k = 0; k < 10; ++k) {
        int slot = (k == 2) ? 3 : (k == 3) ? 2 : k;
        v[k][0] = make_float2(P[slot * 4], P[slot * 4 + 1]);
        v[k][1] = make_float2(P[slot * 4 + 2], P[slot * 4 + 3]);
    }

    for (int i = tid; i < 1024; i += 256) {
        float2 c = ((i >> 9) & 1) ? v[0][1] : v[0][0];
#pragma unroll
        for (int k = 1; k < 10; ++k) {
            float2 vk = ((i >> (9 - k)) & 1) ? v[k][1] : v[k][0];
            c = cmul(c, vk);
        }
        s[i] = c;
    }
    __syncthreads();

    { // CY(ctrl bit7, tgt bit1) + Phase(theta_ps) on bit1
        int j = tid;
        float2 p1 = make_float2(P[40], P[41]);
        int i0 = (j & 1) | (((j >> 1) & 31) << 2) | (((j >> 6) & 3) << 8) | 128;
        int i1 = i0 | 2;
        float2 t0 = s[i0], t1 = s[i1];
        s[i0] = make_float2(t1.y, -t1.x);
        s[i1] = cmul(make_float2(-t0.y, t0.x), p1);
        int i2 = (j & 1) | 2 | (((j >> 1) & 31) << 2) | (((j >> 6) & 3) << 8);
        s[i2] = cmul(s[i2], p1);
    }
    __syncthreads();
    if (tid < 128) {
        int j = tid;
        int i0 = (j & 7) | 16 | 32 | (((j >> 3) & 15) << 6);
        int i1 = i0 ^ 0x18;
        float2 t0 = s[i0], t1 = s[i1];
        s[i0] = t1; s[i1] = t0;
    }
    __syncthreads();
    if (tid < 128) {
        int j = tid;
        int i0 = (j & 1) | 2 | (((j >> 1) & 3) << 2) | 16 | (((j >> 3) & 15) << 5);
        int i1 = i0 | 512;
        float2 t0 = s[i0], t1 = s[i1];
        s[i0] = t1; s[i1] = t0;
    }
    __syncthreads();
    apply_rot2(s, 5, make_float2(P[44], P[45]), make_float2(P[46], P[47]),
               make_float2(P[48], P[49]), make_float2(P[50], P[51]), tid);
    __syncthreads();
    apply_rot2(s, 4, make_float2(P[52], P[53]), make_float2(P[54], P[55]),
               make_float2(P[56], P[57]), make_float2(P[58], P[59]), tid);
    __syncthreads();

    int wave = tid >> 6;
    for (int k = 0; k < 10; ++k) {
        int p = 9 - k;
        float part_ = 0.f;
        for (int q = tid; q < 512; q += 256) {
            int i0 = ((q >> p) << (p + 1)) | (q & ((1 << p) - 1));
            int i1 = i0 | (1 << p);
            float2 aa = s[i0], bb = s[i1];
            part_ += aa.x * bb.y - aa.y * bb.x;
        }
        part_ *= 2.f;
#pragma unroll
        for (int off = 32; off > 0; off >>= 1)
            part_ += __shfl_down(part_, off, 64);
        if ((tid & 63) == 0) red[k * 4 + wave] = part_;
    }
    __syncthreads();
    if (tid == 0) {
        float ev[10];
        float mx = -1e30f;
#pragma unroll
        for (int k = 0; k < 10; ++k) {
            ev[k] = red[k * 4] + red[k * 4 + 1] + red[k * 4 + 2] + red[k * 4 + 3];
            mx = fmaxf(mx, ev[k]);
        }
        float sum = 0.f;
#pragma unroll
        for (int k = 0; k < 10; ++k) sum += expf(ev[k] - mx);
        float lse = mx + logf(sum);
#pragma unroll
        for (int k = 0; k < 10; ++k) out[b * 10 + k] = ev[k] - lse;
    }
}

extern "C" void kernel_launch(void* const* d_in, const int* in_sizes, int n_in,
                              void* d_out, int out_size, void* d_ws, size_t ws_size,
                              hipStream_t stream)
{
    (void)in_sizes; (void)n_in; (void)out_size; (void)ws_size;
    const float* x    = (const float*)d_in[0];
    const float* c1w  = (const float*)d_in[1];
    const float* c1b  = (const float*)d_in[2];
    const float* c2w  = (const float*)d_in[3];
    const float* c2b  = (const float*)d_in[4];
    const float* f1w  = (const float*)d_in[5];
    const float* f1b  = (const float*)d_in[6];
    const float* f2w  = (const float*)d_in[7];
    const float* f2b  = (const float*)d_in[8];
    const float* th0  = (const float*)d_in[9];
    const float* trz  = (const float*)d_in[10];
    const float* tps  = (const float*)d_in[11];
    const float* rotp = (const float*)d_in[12];
    float* out = (float*)d_out;

    char* ws = (char*)d_ws;
    ushort* pooled = (ushort*)(ws);                       // 37,748,736 B
    ushort* wt2    = (ushort*)(ws + 37748736);            //     36,864 B
    ushort* wf1    = (ushort*)(ws + 37785600);            //  2,359,296 B
    float*  part   = (float*)(ws + 40144896);             //  4,194,304 B

    prep_kernel<<<4680, 256, 0, stream>>>(c2w, f1w, wt2, wf1);
    conv2_fused<<<256, 512, 0, stream>>>(x, c1w, c1b, wt2, c2b, pooled);
    fc1_mfma<<<dim3(64, 4), 256, 0, stream>>>(pooled, wf1, part);
    quantum_kernel<<<2048, 256, 0, stream>>>(part, f1b, f2w, f2b, th0, trz, tps, rotp, out);
}